// Round 1
// baseline (727.146 us; speedup 1.0000x reference)
//
#include <hip/hip_runtime.h>
#include <hip/hip_bf16.h>
#include <stdint.h>

#define B_  16
#define N_  2048
#define D_  2
#define H_  128
#define CH_ 32
#define NEG_ (-1e9f)

typedef __attribute__((ext_vector_type(8))) short bf16x8;   // 8 bf16 = 4 VGPRs
typedef __attribute__((ext_vector_type(4))) float f32x4;    // MFMA C/D
typedef unsigned short u16;

__device__ inline u16 f2bf(float f){
    union { __hip_bfloat16 h; u16 u; } cv;
    cv.h = __float2bfloat16(f);
    return cv.u;
}
__device__ inline float bf2f(u16 v){ return __uint_as_float(((unsigned)v) << 16); }

// ---------------------------------------------------------------------------
// K0: fused adj transpose (int -> bf16 with self-loops) + column-degree sums
// ATbf[b,i,j] = A[b,j,i],  A = (adj!=0) || (j==i);  degF[b,i] += sum_j A[b,j,i]
// ---------------------------------------------------------------------------
__global__ __launch_bounds__(256) void k_prep(const int* __restrict__ adj,
                                              u16* __restrict__ ATbf,
                                              float* __restrict__ degF){
    int i0 = blockIdx.x * 64, j0 = blockIdx.y * 64, b = blockIdx.z;
    __shared__ u16 tile[64 * 66];
    __shared__ float degP[256];
    int t = threadIdx.x;
    int ii = t & 63, tq = t >> 6;            // ii fixed per thread, tq in [0,4)
    const int* ap = adj + (size_t)b * N_ * N_;
    float cnt = 0.f;
    #pragma unroll
    for (int it = 0; it < 16; ++it){
        int jj = tq + it * 4;
        int gi = i0 + ii, gj = j0 + jj;
        int a  = ap[(size_t)gj * N_ + gi];
        int one = (a != 0) || (gj == gi);
        tile[ii * 66 + jj] = one ? (u16)0x3F80 : (u16)0;   // bf16(1.0)
        cnt += (float)one;
    }
    degP[t] = cnt;
    __syncthreads();
    if (t < 64){
        float s = degP[t] + degP[t + 64] + degP[t + 128] + degP[t + 192];
        atomicAdd(&degF[b * N_ + i0 + t], s);
    }
    u16* op = ATbf + (size_t)b * N_ * N_;
    #pragma unroll
    for (int it = 0; it < 16; ++it){
        int idx = it * 256 + t;
        int io = idx >> 6, jo = idx & 63;
        op[(size_t)(i0 + io) * N_ + j0 + jo] = tile[io * 66 + jo];
    }
}

__global__ void k_dis(const float* __restrict__ degF, float* __restrict__ dis){
    int i = blockIdx.x * 256 + threadIdx.x;
    dis[i] = rsqrtf(degF[i]);
}

// ---------------------------------------------------------------------------
// K1: layer-1 input in transposed land: Y1T[b,h,j] = dis[b,j]*(f0*W1[0,h]+f1*W1[1,h])
// ---------------------------------------------------------------------------
__global__ __launch_bounds__(256) void k_y1(const float* __restrict__ feat,
                                            const float* __restrict__ W1,
                                            const float* __restrict__ dis,
                                            u16* __restrict__ YT){
    int j = blockIdx.x * 256 + threadIdx.x;
    int h = blockIdx.y, b = blockIdx.z;
    float f0 = feat[((size_t)b * N_ + j) * D_ + 0];
    float f1 = feat[((size_t)b * N_ + j) * D_ + 1];
    float v = dis[b * N_ + j] * (f0 * W1[h] + f1 * W1[H_ + h]);
    YT[(size_t)b * H_ * N_ + (size_t)h * N_ + j] = f2bf(v);
}

// ---------------------------------------------------------------------------
// 128x128 fp32 -> bf16 transpose (for W2, W3, A1[:128], A2)
// ---------------------------------------------------------------------------
__global__ void k_t128(const float* s0, u16* d0, const float* s1, u16* d1,
                       const float* s2, u16* d2, const float* s3, u16* d3){
    const float* s; u16* d;
    switch (blockIdx.y){
        case 0: s = s0; d = d0; break;
        case 1: s = s1; d = d1; break;
        case 2: s = s2; d = d2; break;
        default: s = s3; d = d3; break;
    }
    int idx = blockIdx.x * 256 + threadIdx.x;   // 0..16383
    int hp = idx >> 7, k = idx & 127;
    d[hp * 128 + k] = f2bf(s[k * 128 + hp]);
}

// ---------------------------------------------------------------------------
// K2: GCN layer GEMM.  Z[i,n] = sum_j ATbf[b,i,j] * YT[b,n,j]
// h[b,i,n] = relu(dis[b,i]*Z + bias[n]).   M-tile 64, N=128 full, K=2048.
// ---------------------------------------------------------------------------
__global__ __launch_bounds__(256) void k_gcn(const u16* __restrict__ ATbf,
                                             const u16* __restrict__ YT,
                                             const float* __restrict__ dis,
                                             const float* __restrict__ bias,
                                             u16* __restrict__ hout){
    int b = blockIdx.x, i0 = blockIdx.y * 64;
    const u16* Ab = ATbf + (size_t)b * N_ * N_;
    const u16* Bb = YT   + (size_t)b * H_ * N_;
    __shared__ __align__(16) u16 As[64 * 72];
    __shared__ __align__(16) u16 Bs[128 * 72];
    int t = threadIdx.x, w = t >> 6, lane = t & 63, quad = lane >> 4, l16 = lane & 15;
    f32x4 acc[8];
    #pragma unroll
    for (int nt = 0; nt < 8; ++nt) acc[nt] = (f32x4){0.f, 0.f, 0.f, 0.f};
    int sr = t >> 3, sc = (t & 7) * 8;
    for (int k0 = 0; k0 < N_; k0 += 64){
        *(uint4*)&As[sr * 72 + sc]        = *(const uint4*)&Ab[(size_t)(i0 + sr) * N_ + k0 + sc];
        *(uint4*)&As[(sr + 32) * 72 + sc] = *(const uint4*)&Ab[(size_t)(i0 + sr + 32) * N_ + k0 + sc];
        #pragma unroll
        for (int it = 0; it < 4; ++it)
            *(uint4*)&Bs[(sr + it * 32) * 72 + sc] = *(const uint4*)&Bb[(size_t)(sr + it * 32) * N_ + k0 + sc];
        __syncthreads();
        #pragma unroll
        for (int kc = 0; kc < 2; ++kc){
            bf16x8 af = *(const bf16x8*)&As[(w * 16 + l16) * 72 + kc * 32 + quad * 8];
            #pragma unroll
            for (int nt = 0; nt < 8; ++nt){
                bf16x8 bfr = *(const bf16x8*)&Bs[(nt * 16 + l16) * 72 + kc * 32 + quad * 8];
                acc[nt] = __builtin_amdgcn_mfma_f32_16x16x32_bf16(af, bfr, acc[nt], 0, 0, 0);
            }
        }
        __syncthreads();
    }
    #pragma unroll
    for (int r = 0; r < 4; ++r){
        int m = w * 16 + quad * 4 + r;
        float dsc = dis[b * N_ + i0 + m];
        #pragma unroll
        for (int nt = 0; nt < 8; ++nt){
            int n = nt * 16 + l16;
            float v = dsc * acc[nt][r] + bias[n];
            hout[((size_t)b * N_ + i0 + m) * H_ + n] = f2bf(v > 0.f ? v : 0.f);
        }
    }
}

// ---------------------------------------------------------------------------
// K3: next-layer input:  YT[b,h',j] = dis[b,j] * sum_k h[b,j,k] * W[k,h']
// A = h rows (K-contig), B = WT (pre-transposed).  Transposed write via LDS.
// ---------------------------------------------------------------------------
__global__ __launch_bounds__(256) void k_xw(const u16* __restrict__ hbuf,
                                            const u16* __restrict__ WT,
                                            const float* __restrict__ dis,
                                            u16* __restrict__ YT){
    int bt = blockIdx.x;
    int b = bt >> 4, j0 = (bt & 15) * 128;
    const u16* Ab = hbuf + ((size_t)b * N_ + j0) * H_;
    __shared__ __align__(16) u16 As[128 * 72];
    __shared__ __align__(16) u16 Bs[128 * 72];
    __shared__ __align__(16) u16 Cs[128 * 130];
    int t = threadIdx.x, w = t >> 6, lane = t & 63, quad = lane >> 4, l16 = lane & 15;
    f32x4 acc[2][8];
    #pragma unroll
    for (int mt = 0; mt < 2; ++mt)
        #pragma unroll
        for (int nt = 0; nt < 8; ++nt) acc[mt][nt] = (f32x4){0.f, 0.f, 0.f, 0.f};
    int sr = t >> 3, sc = (t & 7) * 8;
    for (int k0 = 0; k0 < H_; k0 += 64){
        #pragma unroll
        for (int it = 0; it < 4; ++it){
            int r = sr + it * 32;
            *(uint4*)&As[r * 72 + sc] = *(const uint4*)&Ab[(size_t)r * H_ + k0 + sc];
            *(uint4*)&Bs[r * 72 + sc] = *(const uint4*)&WT[(size_t)r * H_ + k0 + sc];
        }
        __syncthreads();
        #pragma unroll
        for (int kc = 0; kc < 2; ++kc){
            bf16x8 af[2];
            #pragma unroll
            for (int mt = 0; mt < 2; ++mt)
                af[mt] = *(const bf16x8*)&As[(w * 32 + mt * 16 + l16) * 72 + kc * 32 + quad * 8];
            #pragma unroll
            for (int nt = 0; nt < 8; ++nt){
                bf16x8 bfr = *(const bf16x8*)&Bs[(nt * 16 + l16) * 72 + kc * 32 + quad * 8];
                #pragma unroll
                for (int mt = 0; mt < 2; ++mt)
                    acc[mt][nt] = __builtin_amdgcn_mfma_f32_16x16x32_bf16(af[mt], bfr, acc[mt][nt], 0, 0, 0);
            }
        }
        __syncthreads();
    }
    #pragma unroll
    for (int mt = 0; mt < 2; ++mt)
        #pragma unroll
        for (int r = 0; r < 4; ++r){
            int m = w * 32 + mt * 16 + quad * 4 + r;
            float dsc = dis[b * N_ + j0 + m];
            #pragma unroll
            for (int nt = 0; nt < 8; ++nt){
                int n = nt * 16 + l16;
                Cs[m * 130 + n] = f2bf(dsc * acc[mt][nt][r]);
            }
        }
    __syncthreads();
    #pragma unroll 4
    for (int it = 0; it < 64; ++it){
        int hr = it * 2 + (t >> 7), jj = t & 127;
        YT[(size_t)b * H_ * N_ + (size_t)hr * N_ + j0 + jj] = Cs[jj * 130 + hr];
    }
}

// ---------------------------------------------------------------------------
// K4a: pool partial sums:  poolF[b,h] += (1/N) * sum_i h3[b,i,h]
// ---------------------------------------------------------------------------
__global__ __launch_bounds__(256) void k_pool(const u16* __restrict__ h3,
                                              float* __restrict__ poolF){
    int ic = blockIdx.x, b = blockIdx.y;
    int t = threadIdx.x, h = t & 127, io = t >> 7;
    const u16* p = h3 + ((size_t)b * N_ + ic * 128) * H_;
    float s = 0.f;
    #pragma unroll 4
    for (int it = 0; it < 64; ++it)
        s += bf2f(p[(size_t)(it * 2 + io) * H_ + h]);
    __shared__ float red[256];
    red[t] = s;
    __syncthreads();
    if (t < 128) atomicAdd(&poolF[b * H_ + t], (red[t] + red[t + 128]) * (1.f / N_));
}

// ---------------------------------------------------------------------------
// K4b: cvec[b,h'] = ab1 + pool@A1[128:256] + ms@A1[256:384];  value head -> out[48+b]
// ---------------------------------------------------------------------------
__global__ __launch_bounds__(256) void k_cv(const float* __restrict__ poolF,
                                            const float* __restrict__ ms,
                                            const float* __restrict__ A1,
                                            const float* __restrict__ ab1,
                                            const float* __restrict__ C1,
                                            const float* __restrict__ cb1,
                                            const float* __restrict__ C2,
                                            const float* __restrict__ cb2,
                                            float* __restrict__ cvec,
                                            float* __restrict__ out){
    int b = blockIdx.x, t = threadIdx.x;
    __shared__ float pl[128], msl[128], v1[32];
    if (t < 128){ pl[t] = poolF[b * H_ + t]; msl[t] = ms[t]; }
    __syncthreads();
    if (t < 128){
        float c = ab1[t];
        for (int k = 0; k < 128; ++k)
            c += pl[k] * A1[(128 + k) * H_ + t] + msl[k] * A1[(256 + k) * H_ + t];
        cvec[b * H_ + t] = c;
    } else if (t < 160){
        int cc = t - 128;
        float v = cb1[cc];
        for (int k = 0; k < 128; ++k) v += pl[k] * C1[k * CH_ + cc];
        v1[cc] = v > 0.f ? v : 0.f;
    }
    __syncthreads();
    if (t == 0){
        float v = cb2[0];
        for (int c = 0; c < CH_; ++c) v += v1[c] * C2[c];
        out[48 + b] = v;
    }
}

// ---------------------------------------------------------------------------
// K5: actor MLP: a1=relu(h3@A1a+cvec); a2=relu(a1@A2+ab2); scores=(a2@A3+ab3)*10
// ---------------------------------------------------------------------------
__global__ __launch_bounds__(256) void k_actor(const u16* __restrict__ h3,
                                               const u16* __restrict__ A1aT,
                                               const u16* __restrict__ A2T,
                                               const float* __restrict__ cvec,
                                               const float* __restrict__ ab2,
                                               const float* __restrict__ A3,
                                               const float* __restrict__ ab3,
                                               float* __restrict__ scores){
    int b = blockIdx.x, i0 = blockIdx.y * 128;
    const u16* Ab = h3 + ((size_t)b * N_ + i0) * H_;
    __shared__ __align__(16) u16 As[128 * 72];
    __shared__ __align__(16) u16 Bs[128 * 72];
    __shared__ __align__(16) u16 M1[128 * 136];
    __shared__ float sLDS[128];
    int t = threadIdx.x, w = t >> 6, lane = t & 63, quad = lane >> 4, l16 = lane & 15;
    int sr = t >> 3, sc = (t & 7) * 8;
    f32x4 acc[2][8];
    #pragma unroll
    for (int mt = 0; mt < 2; ++mt)
        #pragma unroll
        for (int nt = 0; nt < 8; ++nt) acc[mt][nt] = (f32x4){0.f, 0.f, 0.f, 0.f};
    // GEMM1: h3 @ A1a
    for (int k0 = 0; k0 < H_; k0 += 64){
        #pragma unroll
        for (int it = 0; it < 4; ++it){
            int r = sr + it * 32;
            *(uint4*)&As[r * 72 + sc] = *(const uint4*)&Ab[(size_t)r * H_ + k0 + sc];
            *(uint4*)&Bs[r * 72 + sc] = *(const uint4*)&A1aT[(size_t)r * H_ + k0 + sc];
        }
        __syncthreads();
        #pragma unroll
        for (int kc = 0; kc < 2; ++kc){
            bf16x8 af[2];
            #pragma unroll
            for (int mt = 0; mt < 2; ++mt)
                af[mt] = *(const bf16x8*)&As[(w * 32 + mt * 16 + l16) * 72 + kc * 32 + quad * 8];
            #pragma unroll
            for (int nt = 0; nt < 8; ++nt){
                bf16x8 bfr = *(const bf16x8*)&Bs[(nt * 16 + l16) * 72 + kc * 32 + quad * 8];
                #pragma unroll
                for (int mt = 0; mt < 2; ++mt)
                    acc[mt][nt] = __builtin_amdgcn_mfma_f32_16x16x32_bf16(af[mt], bfr, acc[mt][nt], 0, 0, 0);
            }
        }
        __syncthreads();
    }
    // a1 = relu(acc + cvec) -> M1 (A-operand layout for GEMM2)
    const float* cv = cvec + b * H_;
    #pragma unroll
    for (int mt = 0; mt < 2; ++mt)
        #pragma unroll
        for (int r = 0; r < 4; ++r){
            int m = w * 32 + mt * 16 + quad * 4 + r;
            #pragma unroll
            for (int nt = 0; nt < 8; ++nt){
                int n = nt * 16 + l16;
                float v = acc[mt][nt][r] + cv[n];
                M1[m * 136 + n] = f2bf(v > 0.f ? v : 0.f);
                acc[mt][nt][r] = 0.f;   // reset for GEMM2
            }
        }
    if (t < 128) sLDS[t] = 0.f;
    // GEMM2: a1 @ A2
    for (int k0 = 0; k0 < H_; k0 += 64){
        #pragma unroll
        for (int it = 0; it < 4; ++it){
            int r = sr + it * 32;
            *(uint4*)&Bs[r * 72 + sc] = *(const uint4*)&A2T[(size_t)r * H_ + k0 + sc];
        }
        __syncthreads();
        #pragma unroll
        for (int kc = 0; kc < 2; ++kc){
            bf16x8 af[2];
            #pragma unroll
            for (int mt = 0; mt < 2; ++mt)
                af[mt] = *(const bf16x8*)&M1[(w * 32 + mt * 16 + l16) * 136 + k0 + kc * 32 + quad * 8];
            #pragma unroll
            for (int nt = 0; nt < 8; ++nt){
                bf16x8 bfr = *(const bf16x8*)&Bs[(nt * 16 + l16) * 72 + kc * 32 + quad * 8];
                #pragma unroll
                for (int mt = 0; mt < 2; ++mt)
                    acc[mt][nt] = __builtin_amdgcn_mfma_f32_16x16x32_bf16(af[mt], bfr, acc[mt][nt], 0, 0, 0);
            }
        }
        __syncthreads();
    }
    // a2 = relu(acc + ab2); per-row dot with A3 -> scores
    #pragma unroll
    for (int mt = 0; mt < 2; ++mt)
        #pragma unroll
        for (int r = 0; r < 4; ++r){
            int m = w * 32 + mt * 16 + quad * 4 + r;
            float part = 0.f;
            #pragma unroll
            for (int nt = 0; nt < 8; ++nt){
                int n = nt * 16 + l16;
                float v = acc[mt][nt][r] + ab2[n];
                v = v > 0.f ? v : 0.f;
                part += v * A3[n];
            }
            atomicAdd(&sLDS[m], part);
        }
    __syncthreads();
    if (t < 128) scores[(size_t)b * N_ + i0 + t] = (sLDS[t] + ab3[0]) * 10.f;
}

// ---------------------------------------------------------------------------
// K6: softmax over scores -> masked log_softmax -> log_prob, entropy, action
// ---------------------------------------------------------------------------
__device__ inline float wredS(float v){
    #pragma unroll
    for (int o = 32; o; o >>= 1) v += __shfl_xor(v, o, 64);
    return v;
}
__device__ inline float wredM(float v){
    #pragma unroll
    for (int o = 32; o; o >>= 1) v = fmaxf(v, __shfl_xor(v, o, 64));
    return v;
}

__global__ __launch_bounds__(256) void k_sm(const float* __restrict__ scores,
                                            const int* __restrict__ cand,
                                            const int* __restrict__ action,
                                            float* __restrict__ out){
    int b = blockIdx.x, t = threadIdx.x;
    __shared__ float sc[N_];
    __shared__ float red[4];
    __shared__ float lps;
    const float* sp = scores + (size_t)b * N_;
    const int*   cp = cand   + (size_t)b * N_;
    float mx = -1e30f;
    for (int i = t; i < N_; i += 256){ float v = sp[i]; sc[i] = v; mx = fmaxf(mx, v); }
    mx = wredM(mx);
    if ((t & 63) == 0) red[t >> 6] = mx;
    __syncthreads();
    mx = fmaxf(fmaxf(red[0], red[1]), fmaxf(red[2], red[3]));
    __syncthreads();
    float se = 0.f;
    for (int i = t; i < N_; i += 256) se += expf(sc[i] - mx);
    se = wredS(se);
    if ((t & 63) == 0) red[t >> 6] = se;
    __syncthreads();
    float s1 = red[0] + red[1] + red[2] + red[3];
    __syncthreads();
    float inv = 1.f / s1;
    float m2 = -1e30f;
    for (int i = t; i < N_; i += 256){
        float p = expf(sc[i] - mx) * inv;
        sc[i] = p;                                   // own slot only
        if (cp[i] != 0) m2 = fmaxf(m2, p);
    }
    m2 = wredM(m2);
    if ((t & 63) == 0) red[t >> 6] = m2;
    __syncthreads();
    m2 = fmaxf(fmaxf(red[0], red[1]), fmaxf(red[2], red[3]));
    __syncthreads();
    float s2 = 0.f;
    for (int i = t; i < N_; i += 256) if (cp[i] != 0) s2 += expf(sc[i] - m2);
    s2 = wredS(s2);
    if ((t & 63) == 0) red[t >> 6] = s2;
    __syncthreads();
    float lse = m2 + logf(red[0] + red[1] + red[2] + red[3]);
    __syncthreads();
    int a = action[b];
    float ent = 0.f;
    for (int i = t; i < N_; i += 256){
        float lp = (cp[i] != 0 ? sc[i] : NEG_) - lse;
        float pe = expf(lp);
        ent -= pe * lp;
        if (i == a) lps = lp;
    }
    ent = wredS(ent);
    if ((t & 63) == 0) red[t >> 6] = ent;
    __syncthreads();
    if (t == 0){
        out[b]      = (float)a;
        out[16 + b] = lps;
        out[32 + b] = red[0] + red[1] + red[2] + red[3];
    }
}

// ---------------------------------------------------------------------------
extern "C" void kernel_launch(void* const* d_in, const int* in_sizes, int n_in,
                              void* d_out, int out_size, void* d_ws, size_t ws_size,
                              hipStream_t stream) {
    const float* feat = (const float*)d_in[0];
    const int*   adj  = (const int*)d_in[1];
    const int*   cand = (const int*)d_in[2];
    const int*   act  = (const int*)d_in[3];
    const float* W1   = (const float*)d_in[4];
    const float* b1   = (const float*)d_in[5];
    const float* W2   = (const float*)d_in[6];
    const float* b2   = (const float*)d_in[7];
    const float* W3   = (const float*)d_in[8];
    const float* b3   = (const float*)d_in[9];
    const float* ms   = (const float*)d_in[10];
    const float* A1   = (const float*)d_in[11];
    const float* ab1  = (const float*)d_in[12];
    const float* A2   = (const float*)d_in[13];
    const float* ab2  = (const float*)d_in[14];
    const float* A3   = (const float*)d_in[15];
    const float* ab3  = (const float*)d_in[16];
    const float* C1   = (const float*)d_in[17];
    const float* cb1  = (const float*)d_in[18];
    const float* C2   = (const float*)d_in[19];
    const float* cb2  = (const float*)d_in[20];
    float* out = (float*)d_out;

    char* w8 = (char*)d_ws;
    size_t off = 0;
    auto alloc = [&](size_t bytes){ void* p = w8 + off; off += (bytes + 255) & ~(size_t)255; return p; };
    u16*   ATbf  = (u16*)  alloc((size_t)B_ * N_ * N_ * 2);
    u16*   YT    = (u16*)  alloc((size_t)B_ * H_ * N_ * 2);
    u16*   hbuf  = (u16*)  alloc((size_t)B_ * N_ * H_ * 2);
    float* degF  = (float*)alloc((size_t)B_ * N_ * 4);
    float* poolF = (float*)alloc((size_t)B_ * H_ * 4);
    float* dis   = (float*)alloc((size_t)B_ * N_ * 4);
    float* cvec  = (float*)alloc((size_t)B_ * H_ * 4);
    float* scr   = (float*)alloc((size_t)B_ * N_ * 4);
    u16*   WT2   = (u16*)  alloc((size_t)H_ * H_ * 2);
    u16*   WT3   = (u16*)  alloc((size_t)H_ * H_ * 2);
    u16*   A1aT  = (u16*)  alloc((size_t)H_ * H_ * 2);
    u16*   A2T   = (u16*)  alloc((size_t)H_ * H_ * 2);

    // zero the accumulation buffers (degF + poolF are adjacent)
    hipMemsetAsync(degF, 0, (size_t)B_ * N_ * 4 + (size_t)B_ * H_ * 4, stream);

    k_prep<<<dim3(32, 32, 16), 256, 0, stream>>>(adj, ATbf, degF);
    k_dis <<<dim3(B_ * N_ / 256), 256, 0, stream>>>(degF, dis);
    k_y1  <<<dim3(8, 128, 16), 256, 0, stream>>>(feat, W1, dis, YT);
    k_t128<<<dim3(64, 4), 256, 0, stream>>>(W2, WT2, W3, WT3, A1, A1aT, A2, A2T);

    k_gcn <<<dim3(16, 32), 256, 0, stream>>>(ATbf, YT, dis, b1, hbuf);
    k_xw  <<<dim3(256), 256, 0, stream>>>(hbuf, WT2, dis, YT);
    k_gcn <<<dim3(16, 32), 256, 0, stream>>>(ATbf, YT, dis, b2, hbuf);
    k_xw  <<<dim3(256), 256, 0, stream>>>(hbuf, WT3, dis, YT);
    k_gcn <<<dim3(16, 32), 256, 0, stream>>>(ATbf, YT, dis, b3, hbuf);

    k_pool<<<dim3(16, 16), 256, 0, stream>>>(hbuf, poolF);
    k_cv  <<<dim3(16), 256, 0, stream>>>(poolF, ms, A1, ab1, C1, cb1, C2, cb2, cvec, out);
    k_actor<<<dim3(16, 16), 256, 0, stream>>>(hbuf, A1aT, A2T, cvec, ab2, A3, ab3, scr);
    k_sm  <<<dim3(16), 256, 0, stream>>>(scr, cand, act, out);
}

// Round 2
// 656.462 us; speedup vs baseline: 1.1077x; 1.1077x over previous
//
#include <hip/hip_runtime.h>
#include <hip/hip_bf16.h>
#include <stdint.h>

#define B_  16
#define N_  2048
#define D_  2
#define H_  128
#define CH_ 32
#define NEG_ (-1e9f)

typedef __attribute__((ext_vector_type(8))) short bf16x8;   // 8 bf16 = 4 VGPRs
typedef __attribute__((ext_vector_type(4))) float f32x4;    // MFMA C/D
typedef unsigned short u16;

__device__ inline u16 f2bf(float f){
    union { __hip_bfloat16 h; u16 u; } cv;
    cv.h = __float2bfloat16(f);
    return cv.u;
}
__device__ inline float bf2f(u16 v){ return __uint_as_float(((unsigned)v) << 16); }

// async global->LDS, 16B per lane; LDS dest = wave-uniform base + lane*16
__device__ inline void gld16(const u16* g, u16* l){
    __builtin_amdgcn_global_load_lds(
        (const __attribute__((address_space(1))) unsigned int*)(const void*)g,
        (__attribute__((address_space(3))) unsigned int*)(void*)l, 16, 0, 0);
}

// ---------------------------------------------------------------------------
// K0: adj transpose (int -> bf16 + self-loops) + column-degree partial sums.
// int4 reads, LDS tile, uint4 stores.
// ---------------------------------------------------------------------------
__global__ __launch_bounds__(256) void k_prep(const int* __restrict__ adj,
                                              u16* __restrict__ ATbf,
                                              float* __restrict__ degF){
    int i0 = blockIdx.x * 64, j0 = blockIdx.y * 64, b = blockIdx.z;
    __shared__ u16 tile[64 * 72];          // tile[ii][jj] = A[j0+jj][i0+ii]
    __shared__ float degP[256];
    int t = threadIdx.x;
    const int* ap = adj + (size_t)b * N_ * N_;
    #pragma unroll
    for (int it = 0; it < 4; ++it){
        int jj = it * 16 + (t >> 4);
        int gi0 = (t & 15) * 4;
        int4 a4 = *(const int4*)&ap[(size_t)(j0 + jj) * N_ + i0 + gi0];
        int gj = j0 + jj;
        tile[(gi0 + 0) * 72 + jj] = (a4.x != 0 || gj == i0 + gi0 + 0) ? (u16)0x3F80 : (u16)0;
        tile[(gi0 + 1) * 72 + jj] = (a4.y != 0 || gj == i0 + gi0 + 1) ? (u16)0x3F80 : (u16)0;
        tile[(gi0 + 2) * 72 + jj] = (a4.z != 0 || gj == i0 + gi0 + 2) ? (u16)0x3F80 : (u16)0;
        tile[(gi0 + 3) * 72 + jj] = (a4.w != 0 || gj == i0 + gi0 + 3) ? (u16)0x3F80 : (u16)0;
    }
    __syncthreads();
    {
        int ii = t & 63, q = t >> 6;
        float s = 0.f;
        #pragma unroll
        for (int k = 0; k < 16; ++k) s += (tile[ii * 72 + q * 16 + k] ? 1.f : 0.f);
        degP[t] = s;
    }
    __syncthreads();
    if (t < 64){
        float s = degP[t] + degP[t + 64] + degP[t + 128] + degP[t + 192];
        atomicAdd(&degF[b * N_ + i0 + t], s);
    }
    u16* op = ATbf + (size_t)b * N_ * N_;
    #pragma unroll
    for (int it = 0; it < 2; ++it){
        int idx = it * 256 + t;
        int io = idx >> 3, jo = (idx & 7) * 8;
        *(uint4*)&op[(size_t)(i0 + io) * N_ + j0 + jo] = *(const uint4*)&tile[io * 72 + jo];
    }
}

// ---------------------------------------------------------------------------
// K0b: dis = rsqrt(deg)  (blocks 0..127)  +  4x 128x128 fp32->bf16 transposes
// (blocks 128..383): W2, W3, A1[:128], A2.
// ---------------------------------------------------------------------------
__global__ __launch_bounds__(256) void k_misc(const float* __restrict__ degF,
                                              float* __restrict__ dis,
                                              const float* __restrict__ W2, u16* __restrict__ WT2,
                                              const float* __restrict__ W3, u16* __restrict__ WT3,
                                              const float* __restrict__ A1, u16* __restrict__ A1aT,
                                              const float* __restrict__ A2, u16* __restrict__ A2T){
    int bx = blockIdx.x;
    if (bx < 128){
        int i = bx * 256 + threadIdx.x;
        dis[i] = rsqrtf(degF[i]);
        return;
    }
    int q = (bx - 128) >> 6;
    const float* s; u16* d;
    switch (q){
        case 0: s = W2; d = WT2; break;
        case 1: s = W3; d = WT3; break;
        case 2: s = A1; d = A1aT; break;
        default: s = A2; d = A2T; break;
    }
    int idx = ((bx - 128) & 63) * 256 + threadIdx.x;   // 0..16383
    int hp = idx >> 7, k = idx & 127;
    d[hp * 128 + k] = f2bf(s[k * 128 + hp]);
}

// ---------------------------------------------------------------------------
// K1: Y1T[b,h,j] = dis[b,j]*(f0*W1[0,h]+f1*W1[1,h])
// ---------------------------------------------------------------------------
__global__ __launch_bounds__(256) void k_y1(const float* __restrict__ feat,
                                            const float* __restrict__ W1,
                                            const float* __restrict__ dis,
                                            u16* __restrict__ YT){
    int j = blockIdx.x * 256 + threadIdx.x;
    int h = blockIdx.y, b = blockIdx.z;
    float f0 = feat[((size_t)b * N_ + j) * D_ + 0];
    float f1 = feat[((size_t)b * N_ + j) * D_ + 1];
    float v = dis[b * N_ + j] * (f0 * W1[h] + f1 * W1[H_ + h]);
    YT[(size_t)b * H_ * N_ + (size_t)h * N_ + j] = f2bf(v);
}

// ---------------------------------------------------------------------------
// K2: fused GCN layer.  Phase 1: Z[m,n] = sum_j AT[i0+m,j]*Yin[n,j]  (M=128,
// N=128, K=2048), h = relu(dis_i*Z + bias) -> LDS.
// MODE=0 (mid layer): phase 2: Yout[h',j] = dis_j * (h @ W)[j,h'] (K=128).
// MODE=1 (last layer): write h3 + mean-pool partial atomicAdd.
// 512 threads (8 waves); global_load_lds 16B staging; unpadded 128x64 tiles.
// ---------------------------------------------------------------------------
template<int MODE>
__global__ __launch_bounds__(512) void k_layer(const u16* __restrict__ ATbf,
                                               const u16* __restrict__ Yin,
                                               const float* __restrict__ dis,
                                               const float* __restrict__ bias,
                                               const u16* __restrict__ WT,
                                               u16* __restrict__ Yout,
                                               u16* __restrict__ h3,
                                               float* __restrict__ poolF){
    int bid = blockIdx.x;
    int b = bid & 15, i0 = (bid >> 4) * 128;   // b in low bits -> same-batch blocks share XCD L2
    const u16* Ab = ATbf + (size_t)b * N_ * N_ + (size_t)i0 * N_;
    const u16* Bb = Yin  + (size_t)b * H_ * N_;
    __shared__ __align__(16) u16 ABs[16384];   // As = [0,8192), Bs = [8192,16384)
    __shared__ __align__(16) u16 Hs[128 * 136];
    u16* As = ABs;
    u16* Bs = ABs + 8192;
    int t = threadIdx.x, w = t >> 6, lane = t & 63, quad = lane >> 4, l16 = lane & 15;
    int srow = lane >> 3, scol = (lane & 7) * 8;
    f32x4 acc[8];
    #pragma unroll
    for (int nt = 0; nt < 8; ++nt) acc[nt] = (f32x4){0.f, 0.f, 0.f, 0.f};

    for (int k0 = 0; k0 < N_; k0 += 64){
        #pragma unroll
        for (int it = 0; it < 4; ++it){
            int chunk = w * 4 + it;            // wave-uniform, 0..31
            if (chunk < 16)
                gld16(Ab + (size_t)(chunk * 8 + srow) * N_ + k0 + scol, As + chunk * 512);
            else
                gld16(Bb + (size_t)((chunk - 16) * 8 + srow) * N_ + k0 + scol, Bs + (chunk - 16) * 512);
        }
        __syncthreads();
        #pragma unroll
        for (int kc = 0; kc < 2; ++kc){
            bf16x8 af = *(const bf16x8*)&As[(w * 16 + l16) * 64 + kc * 32 + quad * 8];
            #pragma unroll
            for (int nt = 0; nt < 8; ++nt){
                bf16x8 bv = *(const bf16x8*)&Bs[(nt * 16 + l16) * 64 + kc * 32 + quad * 8];
                acc[nt] = __builtin_amdgcn_mfma_f32_16x16x32_bf16(af, bv, acc[nt], 0, 0, 0);
            }
        }
        __syncthreads();
    }

    if (MODE == 0){
        // stage WT (128x128 u16 = 32 KB) into ABs while epilogue-1 runs
        #pragma unroll
        for (int it = 0; it < 4; ++it){
            int chunk = w * 4 + it;            // 0..31, 4 rows each
            gld16(WT + (size_t)(chunk * 4 + (lane >> 4)) * 128 + (lane & 15) * 8,
                  ABs + chunk * 512);
        }
    }
    // epilogue 1: h = relu(dis_i * Z + bias) -> Hs
    #pragma unroll
    for (int r = 0; r < 4; ++r){
        int m = w * 16 + quad * 4 + r;
        float dsc = dis[b * N_ + i0 + m];
        #pragma unroll
        for (int nt = 0; nt < 8; ++nt){
            int n = nt * 16 + l16;
            float v = dsc * acc[nt][r] + bias[n];
            Hs[m * 136 + n] = f2bf(v > 0.f ? v : 0.f);
        }
    }
    __syncthreads();

    if (MODE == 0){
        // phase 2: Z2[m,h'] = sum_k Hs[m,k] * WT[h',k]
        f32x4 a2[8];
        #pragma unroll
        for (int nt = 0; nt < 8; ++nt) a2[nt] = (f32x4){0.f, 0.f, 0.f, 0.f};
        #pragma unroll
        for (int kc = 0; kc < 4; ++kc){
            bf16x8 af = *(const bf16x8*)&Hs[(w * 16 + l16) * 136 + kc * 32 + quad * 8];
            #pragma unroll
            for (int nt = 0; nt < 8; ++nt){
                bf16x8 bv = *(const bf16x8*)&ABs[(nt * 16 + l16) * 128 + kc * 32 + quad * 8];
                a2[nt] = __builtin_amdgcn_mfma_f32_16x16x32_bf16(af, bv, a2[nt], 0, 0, 0);
            }
        }
        __syncthreads();   // all Hs reads done before overwrite
        #pragma unroll
        for (int r = 0; r < 4; ++r){
            int m = w * 16 + quad * 4 + r;
            float dsc = dis[b * N_ + i0 + m];
            #pragma unroll
            for (int nt = 0; nt < 8; ++nt)
                Hs[m * 136 + nt * 16 + l16] = f2bf(dsc * a2[nt][r]);
        }
        __syncthreads();
        // transposed write: Yout[b, h', i0 + j]
        size_t obase = (size_t)b * H_ * N_ + i0;
        int j = t & 127, hq = t >> 7;
        #pragma unroll 8
        for (int rep = 0; rep < 32; ++rep){
            int hrow = hq + rep * 4;
            Yout[obase + (size_t)hrow * N_ + j] = Hs[j * 136 + hrow];
        }
    } else {
        // h3 write (vectorized)
        #pragma unroll
        for (int rep = 0; rep < 4; ++rep){
            int idx = rep * 512 + t;
            int row = idx >> 3, col = (idx & 7) * 8;
            *(uint4*)&h3[((size_t)b * N_ + i0 + row) * H_ + col] = *(const uint4*)&Hs[row * 136 + col];
        }
        // mean-pool partials
        __shared__ float pred[512];
        int n = t & 127, rq = t >> 7;
        float ps = 0.f;
        #pragma unroll 8
        for (int r = 0; r < 32; ++r) ps += bf2f(Hs[(rq * 32 + r) * 136 + n]);
        pred[t] = ps;
        __syncthreads();
        if (t < 128)
            atomicAdd(&poolF[b * H_ + t],
                      (pred[t] + pred[t + 128] + pred[t + 256] + pred[t + 384]) * (1.f / N_));
    }
}

// ---------------------------------------------------------------------------
// K4b: cvec[b,h'] = ab1 + pool@A1[128:256] + ms@A1[256:384]; value head
// ---------------------------------------------------------------------------
__global__ __launch_bounds__(256) void k_cv(const float* __restrict__ poolF,
                                            const float* __restrict__ ms,
                                            const float* __restrict__ A1,
                                            const float* __restrict__ ab1,
                                            const float* __restrict__ C1,
                                            const float* __restrict__ cb1,
                                            const float* __restrict__ C2,
                                            const float* __restrict__ cb2,
                                            float* __restrict__ cvec,
                                            float* __restrict__ out){
    int b = blockIdx.x, t = threadIdx.x;
    __shared__ float pl[128], msl[128], v1[32];
    if (t < 128){ pl[t] = poolF[b * H_ + t]; msl[t] = ms[t]; }
    __syncthreads();
    if (t < 128){
        float c = ab1[t];
        for (int k = 0; k < 128; ++k)
            c += pl[k] * A1[(128 + k) * H_ + t] + msl[k] * A1[(256 + k) * H_ + t];
        cvec[b * H_ + t] = c;
    } else if (t < 160){
        int cc = t - 128;
        float v = cb1[cc];
        for (int k = 0; k < 128; ++k) v += pl[k] * C1[k * CH_ + cc];
        v1[cc] = v > 0.f ? v : 0.f;
    }
    __syncthreads();
    if (t == 0){
        float v = cb2[0];
        for (int c = 0; c < CH_; ++c) v += v1[c] * C2[c];
        out[48 + b] = v;
    }
}

// ---------------------------------------------------------------------------
// K5: actor MLP
// ---------------------------------------------------------------------------
__global__ __launch_bounds__(256) void k_actor(const u16* __restrict__ h3,
                                               const u16* __restrict__ A1aT,
                                               const u16* __restrict__ A2T,
                                               const float* __restrict__ cvec,
                                               const float* __restrict__ ab2,
                                               const float* __restrict__ A3,
                                               const float* __restrict__ ab3,
                                               float* __restrict__ scores){
    int b = blockIdx.x, i0 = blockIdx.y * 128;
    const u16* Ab = h3 + ((size_t)b * N_ + i0) * H_;
    __shared__ __align__(16) u16 As[128 * 72];
    __shared__ __align__(16) u16 Bs[128 * 72];
    __shared__ __align__(16) u16 M1[128 * 136];
    __shared__ float sLDS[128];
    int t = threadIdx.x, w = t >> 6, lane = t & 63, quad = lane >> 4, l16 = lane & 15;
    int sr = t >> 3, sc = (t & 7) * 8;
    f32x4 acc[2][8];
    #pragma unroll
    for (int mt = 0; mt < 2; ++mt)
        #pragma unroll
        for (int nt = 0; nt < 8; ++nt) acc[mt][nt] = (f32x4){0.f, 0.f, 0.f, 0.f};
    for (int k0 = 0; k0 < H_; k0 += 64){
        #pragma unroll
        for (int it = 0; it < 4; ++it){
            int r = sr + it * 32;
            *(uint4*)&As[r * 72 + sc] = *(const uint4*)&Ab[(size_t)r * H_ + k0 + sc];
            *(uint4*)&Bs[r * 72 + sc] = *(const uint4*)&A1aT[(size_t)r * H_ + k0 + sc];
        }
        __syncthreads();
        #pragma unroll
        for (int kc = 0; kc < 2; ++kc){
            bf16x8 af[2];
            #pragma unroll
            for (int mt = 0; mt < 2; ++mt)
                af[mt] = *(const bf16x8*)&As[(w * 32 + mt * 16 + l16) * 72 + kc * 32 + quad * 8];
            #pragma unroll
            for (int nt = 0; nt < 8; ++nt){
                bf16x8 bfr = *(const bf16x8*)&Bs[(nt * 16 + l16) * 72 + kc * 32 + quad * 8];
                #pragma unroll
                for (int mt = 0; mt < 2; ++mt)
                    acc[mt][nt] = __builtin_amdgcn_mfma_f32_16x16x32_bf16(af[mt], bfr, acc[mt][nt], 0, 0, 0);
            }
        }
        __syncthreads();
    }
    const float* cv = cvec + b * H_;
    #pragma unroll
    for (int mt = 0; mt < 2; ++mt)
        #pragma unroll
        for (int r = 0; r < 4; ++r){
            int m = w * 32 + mt * 16 + quad * 4 + r;
            #pragma unroll
            for (int nt = 0; nt < 8; ++nt){
                int n = nt * 16 + l16;
                float v = acc[mt][nt][r] + cv[n];
                M1[m * 136 + n] = f2bf(v > 0.f ? v : 0.f);
                acc[mt][nt][r] = 0.f;
            }
        }
    if (t < 128) sLDS[t] = 0.f;
    for (int k0 = 0; k0 < H_; k0 += 64){
        #pragma unroll
        for (int it = 0; it < 4; ++it){
            int r = sr + it * 32;
            *(uint4*)&Bs[r * 72 + sc] = *(const uint4*)&A2T[(size_t)r * H_ + k0 + sc];
        }
        __syncthreads();
        #pragma unroll
        for (int kc = 0; kc < 2; ++kc){
            bf16x8 af[2];
            #pragma unroll
            for (int mt = 0; mt < 2; ++mt)
                af[mt] = *(const bf16x8*)&M1[(w * 32 + mt * 16 + l16) * 136 + k0 + kc * 32 + quad * 8];
            #pragma unroll
            for (int nt = 0; nt < 8; ++nt){
                bf16x8 bfr = *(const bf16x8*)&Bs[(nt * 16 + l16) * 72 + kc * 32 + quad * 8];
                #pragma unroll
                for (int mt = 0; mt < 2; ++mt)
                    acc[mt][nt] = __builtin_amdgcn_mfma_f32_16x16x32_bf16(af[mt], bfr, acc[mt][nt], 0, 0, 0);
            }
        }
        __syncthreads();
    }
    #pragma unroll
    for (int mt = 0; mt < 2; ++mt)
        #pragma unroll
        for (int r = 0; r < 4; ++r){
            int m = w * 32 + mt * 16 + quad * 4 + r;
            float part = 0.f;
            #pragma unroll
            for (int nt = 0; nt < 8; ++nt){
                int n = nt * 16 + l16;
                float v = acc[mt][nt][r] + ab2[n];
                v = v > 0.f ? v : 0.f;
                part += v * A3[n];
            }
            atomicAdd(&sLDS[m], part);
        }
    __syncthreads();
    if (t < 128) scores[(size_t)b * N_ + i0 + t] = (sLDS[t] + ab3[0]) * 10.f;
}

// ---------------------------------------------------------------------------
// K6: softmax -> masked log_softmax -> log_prob, entropy
// ---------------------------------------------------------------------------
__device__ inline float wredS(float v){
    #pragma unroll
    for (int o = 32; o; o >>= 1) v += __shfl_xor(v, o, 64);
    return v;
}
__device__ inline float wredM(float v){
    #pragma unroll
    for (int o = 32; o; o >>= 1) v = fmaxf(v, __shfl_xor(v, o, 64));
    return v;
}

__global__ __launch_bounds__(256) void k_sm(const float* __restrict__ scores,
                                            const int* __restrict__ cand,
                                            const int* __restrict__ action,
                                            float* __restrict__ out){
    int b = blockIdx.x, t = threadIdx.x;
    __shared__ float sc[N_];
    __shared__ float red[4];
    __shared__ float lps;
    const float* sp = scores + (size_t)b * N_;
    const int*   cp = cand   + (size_t)b * N_;
    float mx = -1e30f;
    for (int i = t; i < N_; i += 256){ float v = sp[i]; sc[i] = v; mx = fmaxf(mx, v); }
    mx = wredM(mx);
    if ((t & 63) == 0) red[t >> 6] = mx;
    __syncthreads();
    mx = fmaxf(fmaxf(red[0], red[1]), fmaxf(red[2], red[3]));
    __syncthreads();
    float se = 0.f;
    for (int i = t; i < N_; i += 256) se += expf(sc[i] - mx);
    se = wredS(se);
    if ((t & 63) == 0) red[t >> 6] = se;
    __syncthreads();
    float s1 = red[0] + red[1] + red[2] + red[3];
    __syncthreads();
    float inv = 1.f / s1;
    float m2 = -1e30f;
    for (int i = t; i < N_; i += 256){
        float p = expf(sc[i] - mx) * inv;
        sc[i] = p;
        if (cp[i] != 0) m2 = fmaxf(m2, p);
    }
    m2 = wredM(m2);
    if ((t & 63) == 0) red[t >> 6] = m2;
    __syncthreads();
    m2 = fmaxf(fmaxf(red[0], red[1]), fmaxf(red[2], red[3]));
    __syncthreads();
    float s2 = 0.f;
    for (int i = t; i < N_; i += 256) if (cp[i] != 0) s2 += expf(sc[i] - m2);
    s2 = wredS(s2);
    if ((t & 63) == 0) red[t >> 6] = s2;
    __syncthreads();
    float lse = m2 + logf(red[0] + red[1] + red[2] + red[3]);
    __syncthreads();
    int a = action[b];
    float ent = 0.f;
    for (int i = t; i < N_; i += 256){
        float lp = (cp[i] != 0 ? sc[i] : NEG_) - lse;
        float pe = expf(lp);
        ent -= pe * lp;
        if (i == a) lps = lp;
    }
    ent = wredS(ent);
    if ((t & 63) == 0) red[t >> 6] = ent;
    __syncthreads();
    if (t == 0){
        out[b]      = (float)a;
        out[16 + b] = lps;
        out[32 + b] = red[0] + red[1] + red[2] + red[3];
    }
}

// ---------------------------------------------------------------------------
extern "C" void kernel_launch(void* const* d_in, const int* in_sizes, int n_in,
                              void* d_out, int out_size, void* d_ws, size_t ws_size,
                              hipStream_t stream) {
    const float* feat = (const float*)d_in[0];
    const int*   adj  = (const int*)d_in[1];
    const int*   cand = (const int*)d_in[2];
    const int*   act  = (const int*)d_in[3];
    const float* W1   = (const float*)d_in[4];
    const float* b1   = (const float*)d_in[5];
    const float* W2   = (const float*)d_in[6];
    const float* b2   = (const float*)d_in[7];
    const float* W3   = (const float*)d_in[8];
    const float* b3   = (const float*)d_in[9];
    const float* ms   = (const float*)d_in[10];
    const float* A1   = (const float*)d_in[11];
    const float* ab1  = (const float*)d_in[12];
    const float* A2   = (const float*)d_in[13];
    const float* ab2  = (const float*)d_in[14];
    const float* A3   = (const float*)d_in[15];
    const float* ab3  = (const float*)d_in[16];
    const float* C1   = (const float*)d_in[17];
    const float* cb1  = (const float*)d_in[18];
    const float* C2   = (const float*)d_in[19];
    const float* cb2  = (const float*)d_in[20];
    float* out = (float*)d_out;

    char* w8 = (char*)d_ws;
    size_t off = 0;
    auto alloc = [&](size_t bytes){ void* p = w8 + off; off += (bytes + 255) & ~(size_t)255; return p; };
    u16*   ATbf  = (u16*)  alloc((size_t)B_ * N_ * N_ * 2);
    u16*   YTa   = (u16*)  alloc((size_t)B_ * H_ * N_ * 2);
    u16*   YTb   = (u16*)  alloc((size_t)B_ * H_ * N_ * 2);
    u16*   hbuf  = (u16*)  alloc((size_t)B_ * N_ * H_ * 2);
    float* degF  = (float*)alloc((size_t)B_ * N_ * 4);
    float* poolF = (float*)alloc((size_t)B_ * H_ * 4);
    float* dis   = (float*)alloc((size_t)B_ * N_ * 4);
    float* cvec  = (float*)alloc((size_t)B_ * H_ * 4);
    float* scr   = (float*)alloc((size_t)B_ * N_ * 4);
    u16*   WT2   = (u16*)  alloc((size_t)H_ * H_ * 2);
    u16*   WT3   = (u16*)  alloc((size_t)H_ * H_ * 2);
    u16*   A1aT  = (u16*)  alloc((size_t)H_ * H_ * 2);
    u16*   A2T   = (u16*)  alloc((size_t)H_ * H_ * 2);

    // zero deg + pool accumulators (adjacent)
    hipMemsetAsync(degF, 0, (size_t)B_ * N_ * 4 + (size_t)B_ * H_ * 4, stream);

    k_prep<<<dim3(32, 32, 16), 256, 0, stream>>>(adj, ATbf, degF);
    k_misc<<<dim3(384), 256, 0, stream>>>(degF, dis, W2, WT2, W3, WT3, A1, A1aT, A2, A2T);
    k_y1  <<<dim3(8, 128, 16), 256, 0, stream>>>(feat, W1, dis, YTa);

    k_layer<0><<<dim3(256), 512, 0, stream>>>(ATbf, YTa, dis, b1, WT2, YTb, nullptr, nullptr);
    k_layer<0><<<dim3(256), 512, 0, stream>>>(ATbf, YTb, dis, b2, WT3, YTa, nullptr, nullptr);
    k_layer<1><<<dim3(256), 512, 0, stream>>>(ATbf, YTa, dis, b3, nullptr, nullptr, hbuf, poolF);

    k_cv  <<<dim3(16), 256, 0, stream>>>(poolF, ms, A1, ab1, C1, cb1, C2, cb2, cvec, out);
    k_actor<<<dim3(16, 16), 256, 0, stream>>>(hbuf, A1aT, A2T, cvec, ab2, A3, ab3, scr);
    k_sm  <<<dim3(16), 256, 0, stream>>>(scr, cand, act, out);
}

// Round 3
// 582.733 us; speedup vs baseline: 1.2478x; 1.1265x over previous
//
#include <hip/hip_runtime.h>
#include <hip/hip_bf16.h>
#include <stdint.h>

#define B_  16
#define N_  2048
#define D_  2
#define H_  128
#define CH_ 32
#define NEG_ (-1e9f)

typedef __attribute__((ext_vector_type(8))) short bf16x8;   // 8 bf16 = 4 VGPRs
typedef __attribute__((ext_vector_type(4))) float f32x4;    // MFMA C/D
typedef unsigned short u16;

__device__ inline u16 f2bf(float f){
    union { __hip_bfloat16 h; u16 u; } cv;
    cv.h = __float2bfloat16(f);
    return cv.u;
}
__device__ inline float bf2f(u16 v){ return __uint_as_float(((unsigned)v) << 16); }

// async global->LDS, 16B per lane; LDS dest = wave-uniform base + lane*16
__device__ inline void gld16(const u16* g, u16* l){
    __builtin_amdgcn_global_load_lds(
        (const __attribute__((address_space(1))) unsigned int*)(const void*)g,
        (__attribute__((address_space(3))) unsigned int*)(void*)l, 16, 0, 0);
}

// ---------------------------------------------------------------------------
// K0: adj transpose (int -> bf16 + self-loops) + column-degree partial sums.
// ---------------------------------------------------------------------------
__global__ __launch_bounds__(256) void k_prep(const int* __restrict__ adj,
                                              u16* __restrict__ ATbf,
                                              float* __restrict__ degF){
    int i0 = blockIdx.x * 64, j0 = blockIdx.y * 64, b = blockIdx.z;
    __shared__ u16 tile[64 * 72];          // tile[ii][jj] = A[j0+jj][i0+ii]
    __shared__ float degP[256];
    int t = threadIdx.x;
    const int* ap = adj + (size_t)b * N_ * N_;
    #pragma unroll
    for (int it = 0; it < 4; ++it){
        int jj = it * 16 + (t >> 4);
        int gi0 = (t & 15) * 4;
        int4 a4 = *(const int4*)&ap[(size_t)(j0 + jj) * N_ + i0 + gi0];
        int gj = j0 + jj;
        tile[(gi0 + 0) * 72 + jj] = (a4.x != 0 || gj == i0 + gi0 + 0) ? (u16)0x3F80 : (u16)0;
        tile[(gi0 + 1) * 72 + jj] = (a4.y != 0 || gj == i0 + gi0 + 1) ? (u16)0x3F80 : (u16)0;
        tile[(gi0 + 2) * 72 + jj] = (a4.z != 0 || gj == i0 + gi0 + 2) ? (u16)0x3F80 : (u16)0;
        tile[(gi0 + 3) * 72 + jj] = (a4.w != 0 || gj == i0 + gi0 + 3) ? (u16)0x3F80 : (u16)0;
    }
    __syncthreads();
    {
        int ii = t & 63, q = t >> 6;
        float s = 0.f;
        #pragma unroll
        for (int k = 0; k < 16; ++k) s += (tile[ii * 72 + q * 16 + k] ? 1.f : 0.f);
        degP[t] = s;
    }
    __syncthreads();
    if (t < 64){
        float s = degP[t] + degP[t + 64] + degP[t + 128] + degP[t + 192];
        atomicAdd(&degF[b * N_ + i0 + t], s);
    }
    u16* op = ATbf + (size_t)b * N_ * N_;
    #pragma unroll
    for (int it = 0; it < 2; ++it){
        int idx = it * 256 + t;
        int io = idx >> 3, jo = (idx & 7) * 8;
        *(uint4*)&op[(size_t)(i0 + io) * N_ + j0 + jo] = *(const uint4*)&tile[io * 72 + jo];
    }
}

// ---------------------------------------------------------------------------
// K0b: dis = rsqrt(deg) (blocks 0..127) + 4x 128x128 fp32->bf16 transposes
// ---------------------------------------------------------------------------
__global__ __launch_bounds__(256) void k_misc(const float* __restrict__ degF,
                                              float* __restrict__ dis,
                                              const float* __restrict__ W2, u16* __restrict__ WT2,
                                              const float* __restrict__ W3, u16* __restrict__ WT3,
                                              const float* __restrict__ A1, u16* __restrict__ A1aT,
                                              const float* __restrict__ A2, u16* __restrict__ A2T){
    int bx = blockIdx.x;
    if (bx < 128){
        int i = bx * 256 + threadIdx.x;
        dis[i] = rsqrtf(degF[i]);
        return;
    }
    int q = (bx - 128) >> 6;
    const float* s; u16* d;
    switch (q){
        case 0: s = W2; d = WT2; break;
        case 1: s = W3; d = WT3; break;
        case 2: s = A1; d = A1aT; break;
        default: s = A2; d = A2T; break;
    }
    int idx = ((bx - 128) & 63) * 256 + threadIdx.x;
    int hp = idx >> 7, k = idx & 127;
    d[hp * 128 + k] = f2bf(s[k * 128 + hp]);
}

// ---------------------------------------------------------------------------
// K1: Y1T[b,h,j] = dis[b,j]*(f0*W1[0,h]+f1*W1[1,h])
// ---------------------------------------------------------------------------
__global__ __launch_bounds__(256) void k_y1(const float* __restrict__ feat,
                                            const float* __restrict__ W1,
                                            const float* __restrict__ dis,
                                            u16* __restrict__ YT){
    int j = blockIdx.x * 256 + threadIdx.x;
    int h = blockIdx.y, b = blockIdx.z;
    float f0 = feat[((size_t)b * N_ + j) * D_ + 0];
    float f1 = feat[((size_t)b * N_ + j) * D_ + 1];
    float v = dis[b * N_ + j] * (f0 * W1[h] + f1 * W1[H_ + h]);
    YT[(size_t)b * H_ * N_ + (size_t)h * N_ + j] = f2bf(v);
}

// ---------------------------------------------------------------------------
// K2: fused GCN layer.
//   Phase 1: Z[m,n] = sum_j AT[i0+m,j]*Yin[n,j]  (M=64, N=128, K=2048),
//            h = relu(dis_i*Z + bias) -> Hs (LDS).
//   MODE=0: Phase 2: Yout[h',j] = dis_j * (h @ W)[j,h']  (K=128, W in LDS).
//   MODE=1: write h3 + mean-pool partial atomicAdd.
// 256 threads (4 waves, 2x2 wave grid, 32x64 out per wave); grid 512 ->
// 2 blocks/CU (LDS 75 KB). global_load_lds staging with XOR-swizzled source
// column (bank-conflict-free fragment reads, HBM layout unchanged).
// ---------------------------------------------------------------------------
template<int MODE>
__global__ __launch_bounds__(256, 2) void k_layer(const u16* __restrict__ ATbf,
                                                  const u16* __restrict__ Yin,
                                                  const float* __restrict__ dis,
                                                  const float* __restrict__ bias,
                                                  const u16* __restrict__ WT,
                                                  u16* __restrict__ Yout,
                                                  u16* __restrict__ h3,
                                                  float* __restrict__ poolF){
    int bid = blockIdx.x;
    int b = bid & 15, i0 = (bid >> 4) * 64;   // bid%8==b%8 -> batch->XCD affinity
    const u16* Ab = ATbf + (size_t)b * N_ * N_ + (size_t)i0 * N_;
    const u16* Bb = Yin  + (size_t)b * H_ * N_;
    __shared__ __align__(16) u16 As[64 * 64];      // 8 KB
    __shared__ __align__(16) u16 Bs[128 * 64];     // 16 KB
    __shared__ __align__(16) u16 Hs[64 * 136];     // 17 KB
    __shared__ __align__(16) u16 Ws[MODE == 0 ? 128 * 136 : 16];  // 34 KB
    int t = threadIdx.x, w = t >> 6, lane = t & 63, quad = lane >> 4, l16 = lane & 15;
    int mr = w & 1, nc = w >> 1;                   // wave grid 2x2
    int srow = lane >> 3;
    int xcol = ((lane & 7) ^ srow) * 8;            // swizzled source column
    int x7 = l16 & 7;

    if (MODE == 0){
        // stage WT (128x128) into padded Ws once, before K-loop
        #pragma unroll
        for (int it = 0; it < 8; ++it){
            int e = it * 256 + t;
            int row = e >> 4, c8 = e & 15;
            *(uint4*)&Ws[row * 136 + c8 * 8] = *(const uint4*)&WT[row * 128 + c8 * 8];
        }
    }

    f32x4 acc[2][4];
    #pragma unroll
    for (int mt = 0; mt < 2; ++mt)
        #pragma unroll
        for (int nt = 0; nt < 4; ++nt) acc[mt][nt] = (f32x4){0.f, 0.f, 0.f, 0.f};

    for (int k0 = 0; k0 < N_; k0 += 64){
        #pragma unroll
        for (int it = 0; it < 6; ++it){
            int chunk = w * 6 + it;                // wave-uniform, 0..23
            if (chunk < 8)
                gld16(Ab + (size_t)(chunk * 8 + srow) * N_ + k0 + xcol, As + chunk * 512);
            else
                gld16(Bb + (size_t)((chunk - 8) * 8 + srow) * N_ + k0 + xcol, Bs + (chunk - 8) * 512);
        }
        __syncthreads();
        #pragma unroll
        for (int kc = 0; kc < 2; ++kc){
            int gx = ((kc * 4 + quad) ^ x7) * 8;   // de-swizzled chunk offset
            bf16x8 af[2];
            #pragma unroll
            for (int mt = 0; mt < 2; ++mt)
                af[mt] = *(const bf16x8*)&As[(mr * 32 + mt * 16 + l16) * 64 + gx];
            #pragma unroll
            for (int nt = 0; nt < 4; ++nt){
                bf16x8 bv = *(const bf16x8*)&Bs[(nc * 64 + nt * 16 + l16) * 64 + gx];
                #pragma unroll
                for (int mt = 0; mt < 2; ++mt)
                    acc[mt][nt] = __builtin_amdgcn_mfma_f32_16x16x32_bf16(af[mt], bv, acc[mt][nt], 0, 0, 0);
            }
        }
        __syncthreads();
    }

    // epilogue 1: h = relu(dis_i * Z + bias) -> Hs
    #pragma unroll
    for (int mt = 0; mt < 2; ++mt)
        #pragma unroll
        for (int r = 0; r < 4; ++r){
            int m = mr * 32 + mt * 16 + quad * 4 + r;
            float dsc = dis[b * N_ + i0 + m];
            #pragma unroll
            for (int nt = 0; nt < 4; ++nt){
                int n = nc * 64 + nt * 16 + l16;
                float v = dsc * acc[mt][nt][r] + bias[n];
                Hs[m * 136 + n] = f2bf(v > 0.f ? v : 0.f);
            }
        }
    __syncthreads();

    if (MODE == 0){
        // phase 2: Z2[m,h'] = sum_k Hs[m,k] * Ws[h',k]
        f32x4 a2[2][4];
        #pragma unroll
        for (int mt = 0; mt < 2; ++mt)
            #pragma unroll
            for (int nt = 0; nt < 4; ++nt) a2[mt][nt] = (f32x4){0.f, 0.f, 0.f, 0.f};
        #pragma unroll
        for (int kc = 0; kc < 4; ++kc){
            bf16x8 af[2];
            #pragma unroll
            for (int mt = 0; mt < 2; ++mt)
                af[mt] = *(const bf16x8*)&Hs[(mr * 32 + mt * 16 + l16) * 136 + kc * 32 + quad * 8];
            #pragma unroll
            for (int nt = 0; nt < 4; ++nt){
                bf16x8 bv = *(const bf16x8*)&Ws[(nc * 64 + nt * 16 + l16) * 136 + kc * 32 + quad * 8];
                #pragma unroll
                for (int mt = 0; mt < 2; ++mt)
                    a2[mt][nt] = __builtin_amdgcn_mfma_f32_16x16x32_bf16(af[mt], bv, a2[mt][nt], 0, 0, 0);
            }
        }
        __syncthreads();   // all Hs reads done before overwrite
        #pragma unroll
        for (int mt = 0; mt < 2; ++mt)
            #pragma unroll
            for (int r = 0; r < 4; ++r){
                int m = mr * 32 + mt * 16 + quad * 4 + r;
                float dsc = dis[b * N_ + i0 + m];
                #pragma unroll
                for (int nt = 0; nt < 4; ++nt)
                    Hs[m * 136 + nc * 64 + nt * 16 + l16] = f2bf(dsc * a2[mt][nt][r]);
            }
        __syncthreads();
        // transposed write: Yout[b, h', i0 + j]
        size_t obase = (size_t)b * H_ * N_ + i0;
        int j = t & 63, hq = t >> 6;
        #pragma unroll 8
        for (int rep = 0; rep < 32; ++rep){
            int hrow = hq * 32 + rep;
            Yout[obase + (size_t)hrow * N_ + j] = Hs[j * 136 + hrow];
        }
    } else {
        // h3 write (vectorized)
        #pragma unroll
        for (int rep = 0; rep < 4; ++rep){
            int e = rep * 256 + t;
            int row = e >> 4, c8 = e & 15;
            *(uint4*)&h3[((size_t)b * N_ + i0 + row) * H_ + c8 * 8] = *(const uint4*)&Hs[row * 136 + c8 * 8];
        }
        // mean-pool partials
        __shared__ float pred[256];
        int n = t & 127, rq = t >> 7;
        float ps = 0.f;
        #pragma unroll 8
        for (int r = 0; r < 32; ++r) ps += bf2f(Hs[(rq * 32 + r) * 136 + n]);
        pred[t] = ps;
        __syncthreads();
        if (t < 128)
            atomicAdd(&poolF[b * H_ + t], (pred[t] + pred[t + 128]) * (1.f / N_));
    }
}

// ---------------------------------------------------------------------------
// K4b: cvec[b,h'] = ab1 + pool@A1[128:256] + ms@A1[256:384]; value head
// ---------------------------------------------------------------------------
__global__ __launch_bounds__(256) void k_cv(const float* __restrict__ poolF,
                                            const float* __restrict__ ms,
                                            const float* __restrict__ A1,
                                            const float* __restrict__ ab1,
                                            const float* __restrict__ C1,
                                            const float* __restrict__ cb1,
                                            const float* __restrict__ C2,
                                            const float* __restrict__ cb2,
                                            float* __restrict__ cvec,
                                            float* __restrict__ out){
    int b = blockIdx.x, t = threadIdx.x;
    __shared__ float pl[128], msl[128], v1[32];
    if (t < 128){ pl[t] = poolF[b * H_ + t]; msl[t] = ms[t]; }
    __syncthreads();
    if (t < 128){
        float c = ab1[t];
        for (int k = 0; k < 128; ++k)
            c += pl[k] * A1[(128 + k) * H_ + t] + msl[k] * A1[(256 + k) * H_ + t];
        cvec[b * H_ + t] = c;
    } else if (t < 160){
        int cc = t - 128;
        float v = cb1[cc];
        for (int k = 0; k < 128; ++k) v += pl[k] * C1[k * CH_ + cc];
        v1[cc] = v > 0.f ? v : 0.f;
    }
    __syncthreads();
    if (t == 0){
        float v = cb2[0];
        for (int c = 0; c < CH_; ++c) v += v1[c] * C2[c];
        out[48 + b] = v;
    }
}

// ---------------------------------------------------------------------------
// K5: actor MLP
// ---------------------------------------------------------------------------
__global__ __launch_bounds__(256) void k_actor(const u16* __restrict__ h3,
                                               const u16* __restrict__ A1aT,
                                               const u16* __restrict__ A2T,
                                               const float* __restrict__ cvec,
                                               const float* __restrict__ ab2,
                                               const float* __restrict__ A3,
                                               const float* __restrict__ ab3,
                                               float* __restrict__ scores){
    int b = blockIdx.x, i0 = blockIdx.y * 128;
    const u16* Ab = h3 + ((size_t)b * N_ + i0) * H_;
    __shared__ __align__(16) u16 As[128 * 72];
    __shared__ __align__(16) u16 Bs[128 * 72];
    __shared__ __align__(16) u16 M1[128 * 136];
    __shared__ float sLDS[128];
    int t = threadIdx.x, w = t >> 6, lane = t & 63, quad = lane >> 4, l16 = lane & 15;
    int sr = t >> 3, sc = (t & 7) * 8;
    f32x4 acc[2][8];
    #pragma unroll
    for (int mt = 0; mt < 2; ++mt)
        #pragma unroll
        for (int nt = 0; nt < 8; ++nt) acc[mt][nt] = (f32x4){0.f, 0.f, 0.f, 0.f};
    for (int k0 = 0; k0 < H_; k0 += 64){
        #pragma unroll
        for (int it = 0; it < 4; ++it){
            int r = sr + it * 32;
            *(uint4*)&As[r * 72 + sc] = *(const uint4*)&Ab[(size_t)r * H_ + k0 + sc];
            *(uint4*)&Bs[r * 72 + sc] = *(const uint4*)&A1aT[(size_t)r * H_ + k0 + sc];
        }
        __syncthreads();
        #pragma unroll
        for (int kc = 0; kc < 2; ++kc){
            bf16x8 af[2];
            #pragma unroll
            for (int mt = 0; mt < 2; ++mt)
                af[mt] = *(const bf16x8*)&As[(w * 32 + mt * 16 + l16) * 72 + kc * 32 + quad * 8];
            #pragma unroll
            for (int nt = 0; nt < 8; ++nt){
                bf16x8 bfr = *(const bf16x8*)&Bs[(nt * 16 + l16) * 72 + kc * 32 + quad * 8];
                #pragma unroll
                for (int mt = 0; mt < 2; ++mt)
                    acc[mt][nt] = __builtin_amdgcn_mfma_f32_16x16x32_bf16(af[mt], bfr, acc[mt][nt], 0, 0, 0);
            }
        }
        __syncthreads();
    }
    const float* cv = cvec + b * H_;
    #pragma unroll
    for (int mt = 0; mt < 2; ++mt)
        #pragma unroll
        for (int r = 0; r < 4; ++r){
            int m = w * 32 + mt * 16 + quad * 4 + r;
            #pragma unroll
            for (int nt = 0; nt < 8; ++nt){
                int n = nt * 16 + l16;
                float v = acc[mt][nt][r] + cv[n];
                M1[m * 136 + n] = f2bf(v > 0.f ? v : 0.f);
                acc[mt][nt][r] = 0.f;
            }
        }
    if (t < 128) sLDS[t] = 0.f;
    for (int k0 = 0; k0 < H_; k0 += 64){
        #pragma unroll
        for (int it = 0; it < 4; ++it){
            int r = sr + it * 32;
            *(uint4*)&Bs[r * 72 + sc] = *(const uint4*)&A2T[(size_t)r * H_ + k0 + sc];
        }
        __syncthreads();
        #pragma unroll
        for (int kc = 0; kc < 2; ++kc){
            bf16x8 af[2];
            #pragma unroll
            for (int mt = 0; mt < 2; ++mt)
                af[mt] = *(const bf16x8*)&M1[(w * 32 + mt * 16 + l16) * 136 + k0 + kc * 32 + quad * 8];
            #pragma unroll
            for (int nt = 0; nt < 8; ++nt){
                bf16x8 bfr = *(const bf16x8*)&Bs[(nt * 16 + l16) * 72 + kc * 32 + quad * 8];
                #pragma unroll
                for (int mt = 0; mt < 2; ++mt)
                    acc[mt][nt] = __builtin_amdgcn_mfma_f32_16x16x32_bf16(af[mt], bfr, acc[mt][nt], 0, 0, 0);
            }
        }
        __syncthreads();
    }
    #pragma unroll
    for (int mt = 0; mt < 2; ++mt)
        #pragma unroll
        for (int r = 0; r < 4; ++r){
            int m = w * 32 + mt * 16 + quad * 4 + r;
            float part = 0.f;
            #pragma unroll
            for (int nt = 0; nt < 8; ++nt){
                int n = nt * 16 + l16;
                float v = acc[mt][nt][r] + ab2[n];
                v = v > 0.f ? v : 0.f;
                part += v * A3[n];
            }
            atomicAdd(&sLDS[m], part);
        }
    __syncthreads();
    if (t < 128) scores[(size_t)b * N_ + i0 + t] = (sLDS[t] + ab3[0]) * 10.f;
}

// ---------------------------------------------------------------------------
// K6: softmax -> masked log_softmax -> log_prob, entropy
// ---------------------------------------------------------------------------
__device__ inline float wredS(float v){
    #pragma unroll
    for (int o = 32; o; o >>= 1) v += __shfl_xor(v, o, 64);
    return v;
}
__device__ inline float wredM(float v){
    #pragma unroll
    for (int o = 32; o; o >>= 1) v = fmaxf(v, __shfl_xor(v, o, 64));
    return v;
}

__global__ __launch_bounds__(256) void k_sm(const float* __restrict__ scores,
                                            const int* __restrict__ cand,
                                            const int* __restrict__ action,
                                            float* __restrict__ out){
    int b = blockIdx.x, t = threadIdx.x;
    __shared__ float sc[N_];
    __shared__ float red[4];
    __shared__ float lps;
    const float* sp = scores + (size_t)b * N_;
    const int*   cp = cand   + (size_t)b * N_;
    float mx = -1e30f;
    for (int i = t; i < N_; i += 256){ float v = sp[i]; sc[i] = v; mx = fmaxf(mx, v); }
    mx = wredM(mx);
    if ((t & 63) == 0) red[t >> 6] = mx;
    __syncthreads();
    mx = fmaxf(fmaxf(red[0], red[1]), fmaxf(red[2], red[3]));
    __syncthreads();
    float se = 0.f;
    for (int i = t; i < N_; i += 256) se += expf(sc[i] - mx);
    se = wredS(se);
    if ((t & 63) == 0) red[t >> 6] = se;
    __syncthreads();
    float s1 = red[0] + red[1] + red[2] + red[3];
    __syncthreads();
    float inv = 1.f / s1;
    float m2 = -1e30f;
    for (int i = t; i < N_; i += 256){
        float p = expf(sc[i] - mx) * inv;
        sc[i] = p;
        if (cp[i] != 0) m2 = fmaxf(m2, p);
    }
    m2 = wredM(m2);
    if ((t & 63) == 0) red[t >> 6] = m2;
    __syncthreads();
    m2 = fmaxf(fmaxf(red[0], red[1]), fmaxf(red[2], red[3]));
    __syncthreads();
    float s2 = 0.f;
    for (int i = t; i < N_; i += 256) if (cp[i] != 0) s2 += expf(sc[i] - m2);
    s2 = wredS(s2);
    if ((t & 63) == 0) red[t >> 6] = s2;
    __syncthreads();
    float lse = m2 + logf(red[0] + red[1] + red[2] + red[3]);
    __syncthreads();
    int a = action[b];
    float ent = 0.f;
    for (int i = t; i < N_; i += 256){
        float lp = (cp[i] != 0 ? sc[i] : NEG_) - lse;
        float pe = expf(lp);
        ent -= pe * lp;
        if (i == a) lps = lp;
    }
    ent = wredS(ent);
    if ((t & 63) == 0) red[t >> 6] = ent;
    __syncthreads();
    if (t == 0){
        out[b]      = (float)a;
        out[16 + b] = lps;
        out[32 + b] = red[0] + red[1] + red[2] + red[3];
    }
}

// ---------------------------------------------------------------------------
extern "C" void kernel_launch(void* const* d_in, const int* in_sizes, int n_in,
                              void* d_out, int out_size, void* d_ws, size_t ws_size,
                              hipStream_t stream) {
    const float* feat = (const float*)d_in[0];
    const int*   adj  = (const int*)d_in[1];
    const int*   cand = (const int*)d_in[2];
    const int*   act  = (const int*)d_in[3];
    const float* W1   = (const float*)d_in[4];
    const float* b1   = (const float*)d_in[5];
    const float* W2   = (const float*)d_in[6];
    const float* b2   = (const float*)d_in[7];
    const float* W3   = (const float*)d_in[8];
    const float* b3   = (const float*)d_in[9];
    const float* ms   = (const float*)d_in[10];
    const float* A1   = (const float*)d_in[11];
    const float* ab1  = (const float*)d_in[12];
    const float* A2   = (const float*)d_in[13];
    const float* ab2  = (const float*)d_in[14];
    const float* A3   = (const float*)d_in[15];
    const float* ab3  = (const float*)d_in[16];
    const float* C1   = (const float*)d_in[17];
    const float* cb1  = (const float*)d_in[18];
    const float* C2   = (const float*)d_in[19];
    const float* cb2  = (const float*)d_in[20];
    float* out = (float*)d_out;

    char* w8 = (char*)d_ws;
    size_t off = 0;
    auto alloc = [&](size_t bytes){ void* p = w8 + off; off += (bytes + 255) & ~(size_t)255; return p; };
    u16*   ATbf  = (u16*)  alloc((size_t)B_ * N_ * N_ * 2);
    u16*   YTa   = (u16*)  alloc((size_t)B_ * H_ * N_ * 2);
    u16*   YTb   = (u16*)  alloc((size_t)B_ * H_ * N_ * 2);
    u16*   hbuf  = (u16*)  alloc((size_t)B_ * N_ * H_ * 2);
    float* degF  = (float*)alloc((size_t)B_ * N_ * 4);
    float* poolF = (float*)alloc((size_t)B_ * H_ * 4);
    float* dis   = (float*)alloc((size_t)B_ * N_ * 4);
    float* cvec  = (float*)alloc((size_t)B_ * H_ * 4);
    float* scr   = (float*)alloc((size_t)B_ * N_ * 4);
    u16*   WT2   = (u16*)  alloc((size_t)H_ * H_ * 2);
    u16*   WT3   = (u16*)  alloc((size_t)H_ * H_ * 2);
    u16*   A1aT  = (u16*)  alloc((size_t)H_ * H_ * 2);
    u16*   A2T   = (u16*)  alloc((size_t)H_ * H_ * 2);

    // zero deg + pool accumulators (adjacent)
    hipMemsetAsync(degF, 0, (size_t)B_ * N_ * 4 + (size_t)B_ * H_ * 4, stream);

    k_prep<<<dim3(32, 32, 16), 256, 0, stream>>>(adj, ATbf, degF);
    k_misc<<<dim3(384), 256, 0, stream>>>(degF, dis, W2, WT2, W3, WT3, A1, A1aT, A2, A2T);
    k_y1  <<<dim3(8, 128, 16), 256, 0, stream>>>(feat, W1, dis, YTa);

    k_layer<0><<<dim3(512), 256, 0, stream>>>(ATbf, YTa, dis, b1, WT2, YTb, nullptr, nullptr);
    k_layer<0><<<dim3(512), 256, 0, stream>>>(ATbf, YTb, dis, b2, WT3, YTa, nullptr, nullptr);
    k_layer<1><<<dim3(512), 256, 0, stream>>>(ATbf, YTa, dis, b3, nullptr, nullptr, hbuf, poolF);

    k_cv  <<<dim3(16), 256, 0, stream>>>(poolF, ms, A1, ab1, C1, cb1, C2, cb2, cvec, out);
    k_actor<<<dim3(16, 16), 256, 0, stream>>>(hbuf, A1aT, A2T, cvec, ab2, A3, ab3, scr);
    k_sm  <<<dim3(16), 256, 0, stream>>>(scr, cand, act, out);
}

// Round 4
// 561.690 us; speedup vs baseline: 1.2946x; 1.0375x over previous
//
#include <hip/hip_runtime.h>
#include <hip/hip_bf16.h>
#include <stdint.h>

#define B_  16
#define N_  2048
#define D_  2
#define H_  128
#define CH_ 32
#define NEG_ (-1e9f)

typedef __attribute__((ext_vector_type(8))) short bf16x8;   // 8 bf16 = 4 VGPRs
typedef __attribute__((ext_vector_type(4))) float f32x4;    // MFMA C/D
typedef __attribute__((ext_vector_type(4))) int   v4i;      // i8 MFMA operands / i32 acc
typedef unsigned short u16;
typedef signed char    i8;

__device__ inline u16 f2bf(float f){
    union { __hip_bfloat16 h; u16 u; } cv;
    cv.h = __float2bfloat16(f);
    return cv.u;
}
__device__ inline float bf2f(u16 v){ return __uint_as_float(((unsigned)v) << 16); }

// async global->LDS, 16B per lane; LDS dest = wave-uniform base + lane*16
__device__ inline void gld16b(const void* g, void* l){
    __builtin_amdgcn_global_load_lds(
        (const __attribute__((address_space(1))) unsigned int*)g,
        (__attribute__((address_space(3))) unsigned int*)l, 16, 0, 0);
}

__device__ inline float wredS(float v){
    #pragma unroll
    for (int o = 32; o; o >>= 1) v += __shfl_xor(v, o, 64);
    return v;
}
__device__ inline float wredM(float v){
    #pragma unroll
    for (int o = 32; o; o >>= 1) v = fmaxf(v, __shfl_xor(v, o, 64));
    return v;
}

// ---------------------------------------------------------------------------
// K0: adj transpose (int -> i8 {0,1} + self-loops) + column-degree sums.
// ATi8[b,i,j] = (adj[b,j,i]!=0)||(j==i)
// ---------------------------------------------------------------------------
__global__ __launch_bounds__(256) void k_prep(const int* __restrict__ adj,
                                              i8* __restrict__ ATi8,
                                              float* __restrict__ degF){
    int i0 = blockIdx.x * 64, j0 = blockIdx.y * 64, b = blockIdx.z;
    __shared__ i8 tile[64 * 80];           // tile[ii][jj] = A[j0+jj][i0+ii]; stride 80 (16-aligned)
    __shared__ float degP[256];
    int t = threadIdx.x;
    const int* ap = adj + (size_t)b * N_ * N_;
    #pragma unroll
    for (int it = 0; it < 4; ++it){
        int jj = it * 16 + (t >> 4);
        int gi0 = (t & 15) * 4;
        int4 a4 = *(const int4*)&ap[(size_t)(j0 + jj) * N_ + i0 + gi0];
        int gj = j0 + jj;
        tile[(gi0 + 0) * 80 + jj] = (a4.x != 0 || gj == i0 + gi0 + 0) ? 1 : 0;
        tile[(gi0 + 1) * 80 + jj] = (a4.y != 0 || gj == i0 + gi0 + 1) ? 1 : 0;
        tile[(gi0 + 2) * 80 + jj] = (a4.z != 0 || gj == i0 + gi0 + 2) ? 1 : 0;
        tile[(gi0 + 3) * 80 + jj] = (a4.w != 0 || gj == i0 + gi0 + 3) ? 1 : 0;
    }
    __syncthreads();
    {
        int ii = t & 63, q = t >> 6;
        float s = 0.f;
        #pragma unroll
        for (int k = 0; k < 16; ++k) s += (float)tile[ii * 80 + q * 16 + k];
        degP[t] = s;
    }
    __syncthreads();
    if (t < 64){
        float s = degP[t] + degP[t + 64] + degP[t + 128] + degP[t + 192];
        atomicAdd(&degF[b * N_ + i0 + t], s);
    }
    i8* op = ATi8 + (size_t)b * N_ * N_;
    {
        int io = t >> 2, slot = (t & 3) * 16;
        *(uint4*)&op[(size_t)(i0 + io) * N_ + j0 + slot] = *(const uint4*)&tile[io * 80 + slot];
    }
}

// ---------------------------------------------------------------------------
// K0b: dis = rsqrt(deg) (blocks 0..127) + 4x 128x128 fp32->bf16 transposes
// ---------------------------------------------------------------------------
__global__ __launch_bounds__(256) void k_misc(const float* __restrict__ degF,
                                              float* __restrict__ dis,
                                              const float* __restrict__ W2, u16* __restrict__ WT2,
                                              const float* __restrict__ W3, u16* __restrict__ WT3,
                                              const float* __restrict__ A1, u16* __restrict__ A1aT,
                                              const float* __restrict__ A2, u16* __restrict__ A2T){
    int bx = blockIdx.x;
    if (bx < 128){
        int i = bx * 256 + threadIdx.x;
        dis[i] = rsqrtf(degF[i]);
        return;
    }
    int q = (bx - 128) >> 6;
    const float* s; u16* d;
    switch (q){
        case 0: s = W2; d = WT2; break;
        case 1: s = W3; d = WT3; break;
        case 2: s = A1; d = A1aT; break;
        default: s = A2; d = A2T; break;
    }
    int idx = ((bx - 128) & 63) * 256 + threadIdx.x;
    int hp = idx >> 7, k = idx & 127;
    d[hp * 128 + k] = f2bf(s[k * 128 + hp]);
}

// ---------------------------------------------------------------------------
// K1: Y1T[b,h,j] = dis[b,j]*(f0*W1[0,h]+f1*W1[1,h])  (bf16) + per-batch absmax
// ---------------------------------------------------------------------------
__global__ __launch_bounds__(256) void k_y1(const float* __restrict__ feat,
                                            const float* __restrict__ W1,
                                            const float* __restrict__ dis,
                                            u16* __restrict__ YT,
                                            int* __restrict__ absm){
    int t = threadIdx.x;
    int j = blockIdx.x * 256 + t;
    int hg = blockIdx.y * 8;
    int b = blockIdx.z;
    float f0 = feat[((size_t)b * N_ + j) * D_ + 0];
    float f1 = feat[((size_t)b * N_ + j) * D_ + 1];
    float dsc = dis[b * N_ + j];
    float lm = 0.f;
    #pragma unroll
    for (int hh = 0; hh < 8; ++hh){
        int h = hg + hh;
        float v = dsc * (f0 * W1[h] + f1 * W1[H_ + h]);
        lm = fmaxf(lm, fabsf(v));
        YT[(size_t)b * H_ * N_ + (size_t)h * N_ + j] = f2bf(v);
    }
    __shared__ float rmax[256];
    rmax[t] = lm;
    __syncthreads();
    if (t < 128) rmax[t] = fmaxf(rmax[t], rmax[t + 128]);
    __syncthreads();
    if (t < 64){
        float mv = wredM(fmaxf(rmax[t], rmax[t + 64]));
        if (t == 0) atomicMax(&absm[b], __float_as_int(mv));
    }
}

// ---------------------------------------------------------------------------
// K1b: quantize Y bf16 -> i8 with s = 126/absmax[b]
// ---------------------------------------------------------------------------
__global__ __launch_bounds__(256) void k_quant(const u16* __restrict__ Yb,
                                               const int* __restrict__ absm,
                                               i8* __restrict__ Yq){
    int idx = (blockIdx.x * 256 + threadIdx.x) * 8;
    int b = idx >> 18;                    // H_*N_ = 262144
    float am = __int_as_float(absm[b]);
    float s = (am > 0.f) ? 126.f / am : 0.f;
    bf16x8 y = *(const bf16x8*)&Yb[idx];
    int q[8];
    #pragma unroll
    for (int e = 0; e < 8; ++e){
        float f = bf2f((u16)y[e]) * s;
        q[e] = (int)rintf(f);
    }
    unsigned lo = (q[0] & 255) | ((q[1] & 255) << 8) | ((q[2] & 255) << 16) | ((unsigned)(q[3] & 255) << 24);
    unsigned hi = (q[4] & 255) | ((q[5] & 255) << 8) | ((q[6] & 255) << 16) | ((unsigned)(q[7] & 255) << 24);
    *(uint2*)&Yq[idx] = make_uint2(lo, hi);
}

// ---------------------------------------------------------------------------
// K2: fused GCN layer, i8 phase-1 GEMM.
//   Phase 1: Zint[m,n] = sum_j ATi8[i0+m,j]*Yq[n,j]  (M=64, N=128, K=2048),
//            h = relu(dis_i * Zint*inv_s + bias) -> Hs (bf16 LDS).
//   MODE=0: Phase 2 (bf16): Yout[h',j] = dis_j*(h@W)[j,h'] + absmax out.
//   MODE=1: write h3 + mean-pool partial atomicAdd.
// LDS i8 tiles laid out [rowgroup16][slot4(16B)][row16], slot s holds global
// k-slot s^(row&3) -> frag ds_read_b128 is 2-way-per-bank (free).
// ---------------------------------------------------------------------------
template<int MODE>
__global__ __launch_bounds__(256, 2) void k_layer(const i8* __restrict__ ATi8,
                                                  const i8* __restrict__ Yq,
                                                  const float* __restrict__ dis,
                                                  const float* __restrict__ bias,
                                                  const int* __restrict__ absmIn,
                                                  const u16* __restrict__ WT,
                                                  u16* __restrict__ Yout,
                                                  int* __restrict__ absmOut,
                                                  u16* __restrict__ h3,
                                                  float* __restrict__ poolF){
    int bid = blockIdx.x;
    int b = bid & 15, i0 = (bid >> 4) * 64;
    const i8* Ab = ATi8 + (size_t)b * N_ * N_ + (size_t)i0 * N_;
    const i8* Bb = Yq   + (size_t)b * H_ * N_;
    __shared__ __align__(16) i8 As[64 * 64];       // 4 KB  (4 rowgroups)
    __shared__ __align__(16) i8 Bs[128 * 64];      // 8 KB  (8 rowgroups)
    __shared__ __align__(16) u16 Hs[64 * 136];     // 17 KB
    __shared__ __align__(16) u16 Ws[MODE == 0 ? 128 * 136 : 16];
    __shared__ float pmax[256];
    int t = threadIdx.x, w = t >> 6, lane = t & 63, quad = lane >> 4, l16 = lane & 15;
    int mr = w & 1, nc = w >> 1;                   // wave grid 2x2

    float am = __int_as_float(absmIn[b]);
    float inv_s = am * (1.f / 126.f);              // Z = acc * inv_s

    if (MODE == 0){
        #pragma unroll
        for (int it = 0; it < 8; ++it){
            int e = it * 256 + t;
            int row = e >> 4, c8 = e & 15;
            *(uint4*)&Ws[row * 136 + c8 * 8] = *(const uint4*)&WT[row * 128 + c8 * 8];
        }
    }

    v4i acc[2][4];
    #pragma unroll
    for (int mt = 0; mt < 2; ++mt)
        #pragma unroll
        for (int nt = 0; nt < 4; ++nt) acc[mt][nt] = (v4i){0, 0, 0, 0};

    // staging source: lane L of group g reads global row g*16+(L&15),
    // k-col ((L>>4)^(L&3))*16 -> LDS dest g*1024 + L*16 = [slot L>>4][row L&15]
    int srow = lane & 15;
    int sslot = ((lane >> 4) ^ (lane & 3)) * 16;
    int fxo = (quad ^ (l16 & 3)) * 256 + l16 * 16; // frag byte offset within rowgroup

    for (int k0 = 0; k0 < N_; k0 += 64){
        #pragma unroll
        for (int it = 0; it < 3; ++it){
            int g = w * 3 + it;                    // wave-uniform, 0..11
            if (g < 4)
                gld16b(Ab + (size_t)(g * 16 + srow) * N_ + k0 + sslot, As + g * 1024);
            else
                gld16b(Bb + (size_t)((g - 4) * 16 + srow) * N_ + k0 + sslot, Bs + (g - 4) * 1024);
        }
        __syncthreads();
        v4i af[2];
        #pragma unroll
        for (int mt = 0; mt < 2; ++mt)
            af[mt] = *(const v4i*)&As[(mr * 2 + mt) * 1024 + fxo];
        #pragma unroll
        for (int nt = 0; nt < 4; ++nt){
            v4i bv = *(const v4i*)&Bs[(nc * 4 + nt) * 1024 + fxo];
            #pragma unroll
            for (int mt = 0; mt < 2; ++mt)
                acc[mt][nt] = __builtin_amdgcn_mfma_i32_16x16x64_i8(af[mt], bv, acc[mt][nt], 0, 0, 0);
        }
        __syncthreads();
    }

    // epilogue 1: h = relu(dis_i * (acc*inv_s) + bias) -> Hs
    #pragma unroll
    for (int mt = 0; mt < 2; ++mt)
        #pragma unroll
        for (int r = 0; r < 4; ++r){
            int m = mr * 32 + mt * 16 + quad * 4 + r;
            float dsc = dis[b * N_ + i0 + m];
            #pragma unroll
            for (int nt = 0; nt < 4; ++nt){
                int n = nc * 64 + nt * 16 + l16;
                float v = dsc * ((float)acc[mt][nt][r] * inv_s) + bias[n];
                Hs[m * 136 + n] = f2bf(v > 0.f ? v : 0.f);
            }
        }
    __syncthreads();

    if (MODE == 0){
        // phase 2 (bf16): Z2[m,h'] = sum_k Hs[m,k] * Ws[h',k]
        f32x4 a2[2][4];
        #pragma unroll
        for (int mt = 0; mt < 2; ++mt)
            #pragma unroll
            for (int nt = 0; nt < 4; ++nt) a2[mt][nt] = (f32x4){0.f, 0.f, 0.f, 0.f};
        #pragma unroll
        for (int kc = 0; kc < 4; ++kc){
            bf16x8 af[2];
            #pragma unroll
            for (int mt = 0; mt < 2; ++mt)
                af[mt] = *(const bf16x8*)&Hs[(mr * 32 + mt * 16 + l16) * 136 + kc * 32 + quad * 8];
            #pragma unroll
            for (int nt = 0; nt < 4; ++nt){
                bf16x8 bv = *(const bf16x8*)&Ws[(nc * 64 + nt * 16 + l16) * 136 + kc * 32 + quad * 8];
                #pragma unroll
                for (int mt = 0; mt < 2; ++mt)
                    a2[mt][nt] = __builtin_amdgcn_mfma_f32_16x16x32_bf16(af[mt], bv, a2[mt][nt], 0, 0, 0);
            }
        }
        __syncthreads();   // Hs reads done before overwrite
        float lmax = 0.f;
        #pragma unroll
        for (int mt = 0; mt < 2; ++mt)
            #pragma unroll
            for (int r = 0; r < 4; ++r){
                int m = mr * 32 + mt * 16 + quad * 4 + r;
                float dsc = dis[b * N_ + i0 + m];
                #pragma unroll
                for (int nt = 0; nt < 4; ++nt){
                    float v = dsc * a2[mt][nt][r];
                    lmax = fmaxf(lmax, fabsf(v));
                    Hs[m * 136 + nc * 64 + nt * 16 + l16] = f2bf(v);
                }
            }
        pmax[t] = lmax;
        __syncthreads();
        // transposed write: Yout[b, h', i0 + j]
        size_t obase = (size_t)b * H_ * N_ + i0;
        int j = t & 63, hq = t >> 6;
        #pragma unroll 8
        for (int rep = 0; rep < 32; ++rep){
            int hrow = hq * 32 + rep;
            Yout[obase + (size_t)hrow * N_ + j] = Hs[j * 136 + hrow];
        }
        if (t < 64){
            float mv = fmaxf(fmaxf(pmax[t], pmax[t + 64]), fmaxf(pmax[t + 128], pmax[t + 192]));
            mv = wredM(mv);
            if (t == 0) atomicMax(&absmOut[b], __float_as_int(mv));
        }
    } else {
        // h3 write (vectorized)
        #pragma unroll
        for (int rep = 0; rep < 4; ++rep){
            int e = rep * 256 + t;
            int row = e >> 4, c8 = e & 15;
            *(uint4*)&h3[((size_t)b * N_ + i0 + row) * H_ + c8 * 8] = *(const uint4*)&Hs[row * 136 + c8 * 8];
        }
        // mean-pool partials
        int n = t & 127, rq = t >> 7;
        float ps = 0.f;
        #pragma unroll 8
        for (int r = 0; r < 32; ++r) ps += bf2f(Hs[(rq * 32 + r) * 136 + n]);
        pmax[t] = ps;
        __syncthreads();
        if (t < 128)
            atomicAdd(&poolF[b * H_ + t], (pmax[t] + pmax[t + 128]) * (1.f / N_));
    }
}

// ---------------------------------------------------------------------------
// K4b: cvec[b,h'] = ab1 + pool@A1[128:256] + ms@A1[256:384]; value head
// ---------------------------------------------------------------------------
__global__ __launch_bounds__(256) void k_cv(const float* __restrict__ poolF,
                                            const float* __restrict__ ms,
                                            const float* __restrict__ A1,
                                            const float* __restrict__ ab1,
                                            const float* __restrict__ C1,
                                            const float* __restrict__ cb1,
                                            const float* __restrict__ C2,
                                            const float* __restrict__ cb2,
                                            float* __restrict__ cvec,
                                            float* __restrict__ out){
    int b = blockIdx.x, t = threadIdx.x;
    __shared__ float pl[128], msl[128], v1[32];
    if (t < 128){ pl[t] = poolF[b * H_ + t]; msl[t] = ms[t]; }
    __syncthreads();
    if (t < 128){
        float c = ab1[t];
        for (int k = 0; k < 128; ++k)
            c += pl[k] * A1[(128 + k) * H_ + t] + msl[k] * A1[(256 + k) * H_ + t];
        cvec[b * H_ + t] = c;
    } else if (t < 160){
        int cc = t - 128;
        float v = cb1[cc];
        for (int k = 0; k < 128; ++k) v += pl[k] * C1[k * CH_ + cc];
        v1[cc] = v > 0.f ? v : 0.f;
    }
    __syncthreads();
    if (t == 0){
        float v = cb2[0];
        for (int c = 0; c < CH_; ++c) v += v1[c] * C2[c];
        out[48 + b] = v;
    }
}

// ---------------------------------------------------------------------------
// K5: actor MLP (bf16)
// ---------------------------------------------------------------------------
__global__ __launch_bounds__(256) void k_actor(const u16* __restrict__ h3,
                                               const u16* __restrict__ A1aT,
                                               const u16* __restrict__ A2T,
                                               const float* __restrict__ cvec,
                                               const float* __restrict__ ab2,
                                               const float* __restrict__ A3,
                                               const float* __restrict__ ab3,
                                               float* __restrict__ scores){
    int b = blockIdx.x, i0 = blockIdx.y * 128;
    const u16* Ab = h3 + ((size_t)b * N_ + i0) * H_;
    __shared__ __align__(16) u16 As[128 * 72];
    __shared__ __align__(16) u16 Bs[128 * 72];
    __shared__ __align__(16) u16 M1[128 * 136];
    __shared__ float sLDS[128];
    int t = threadIdx.x, w = t >> 6, lane = t & 63, quad = lane >> 4, l16 = lane & 15;
    int sr = t >> 3, sc = (t & 7) * 8;
    f32x4 acc[2][8];
    #pragma unroll
    for (int mt = 0; mt < 2; ++mt)
        #pragma unroll
        for (int nt = 0; nt < 8; ++nt) acc[mt][nt] = (f32x4){0.f, 0.f, 0.f, 0.f};
    for (int k0 = 0; k0 < H_; k0 += 64){
        #pragma unroll
        for (int it = 0; it < 4; ++it){
            int r = sr + it * 32;
            *(uint4*)&As[r * 72 + sc] = *(const uint4*)&Ab[(size_t)r * H_ + k0 + sc];
            *(uint4*)&Bs[r * 72 + sc] = *(const uint4*)&A1aT[(size_t)r * H_ + k0 + sc];
        }
        __syncthreads();
        #pragma unroll
        for (int kc = 0; kc < 2; ++kc){
            bf16x8 af[2];
            #pragma unroll
            for (int mt = 0; mt < 2; ++mt)
                af[mt] = *(const bf16x8*)&As[(w * 32 + mt * 16 + l16) * 72 + kc * 32 + quad * 8];
            #pragma unroll
            for (int nt = 0; nt < 8; ++nt){
                bf16x8 bfr = *(const bf16x8*)&Bs[(nt * 16 + l16) * 72 + kc * 32 + quad * 8];
                #pragma unroll
                for (int mt = 0; mt < 2; ++mt)
                    acc[mt][nt] = __builtin_amdgcn_mfma_f32_16x16x32_bf16(af[mt], bfr, acc[mt][nt], 0, 0, 0);
            }
        }
        __syncthreads();
    }
    const float* cv = cvec + b * H_;
    #pragma unroll
    for (int mt = 0; mt < 2; ++mt)
        #pragma unroll
        for (int r = 0; r < 4; ++r){
            int m = w * 32 + mt * 16 + quad * 4 + r;
            #pragma unroll
            for (int nt = 0; nt < 8; ++nt){
                int n = nt * 16 + l16;
                float v = acc[mt][nt][r] + cv[n];
                M1[m * 136 + n] = f2bf(v > 0.f ? v : 0.f);
                acc[mt][nt][r] = 0.f;
            }
        }
    if (t < 128) sLDS[t] = 0.f;
    for (int k0 = 0; k0 < H_; k0 += 64){
        #pragma unroll
        for (int it = 0; it < 4; ++it){
            int r = sr + it * 32;
            *(uint4*)&Bs[r * 72 + sc] = *(const uint4*)&A2T[(size_t)r * H_ + k0 + sc];
        }
        __syncthreads();
        #pragma unroll
        for (int kc = 0; kc < 2; ++kc){
            bf16x8 af[2];
            #pragma unroll
            for (int mt = 0; mt < 2; ++mt)
                af[mt] = *(const bf16x8*)&M1[(w * 32 + mt * 16 + l16) * 136 + k0 + kc * 32 + quad * 8];
            #pragma unroll
            for (int nt = 0; nt < 8; ++nt){
                bf16x8 bfr = *(const bf16x8*)&Bs[(nt * 16 + l16) * 72 + kc * 32 + quad * 8];
                #pragma unroll
                for (int mt = 0; mt < 2; ++mt)
                    acc[mt][nt] = __builtin_amdgcn_mfma_f32_16x16x32_bf16(af[mt], bfr, acc[mt][nt], 0, 0, 0);
            }
        }
        __syncthreads();
    }
    #pragma unroll
    for (int mt = 0; mt < 2; ++mt)
        #pragma unroll
        for (int r = 0; r < 4; ++r){
            int m = w * 32 + mt * 16 + quad * 4 + r;
            float part = 0.f;
            #pragma unroll
            for (int nt = 0; nt < 8; ++nt){
                int n = nt * 16 + l16;
                float v = acc[mt][nt][r] + ab2[n];
                v = v > 0.f ? v : 0.f;
                part += v * A3[n];
            }
            atomicAdd(&sLDS[m], part);
        }
    __syncthreads();
    if (t < 128) scores[(size_t)b * N_ + i0 + t] = (sLDS[t] + ab3[0]) * 10.f;
}

// ---------------------------------------------------------------------------
// K6: softmax -> masked log_softmax -> log_prob, entropy
// ---------------------------------------------------------------------------
__global__ __launch_bounds__(256) void k_sm(const float* __restrict__ scores,
                                            const int* __restrict__ cand,
                                            const int* __restrict__ action,
                                            float* __restrict__ out){
    int b = blockIdx.x, t = threadIdx.x;
    __shared__ float sc[N_];
    __shared__ float red[4];
    __shared__ float lps;
    const float* sp = scores + (size_t)b * N_;
    const int*   cp = cand   + (size_t)b * N_;
    float mx = -1e30f;
    for (int i = t; i < N_; i += 256){ float v = sp[i]; sc[i] = v; mx = fmaxf(mx, v); }
    mx = wredM(mx);
    if ((t & 63) == 0) red[t >> 6] = mx;
    __syncthreads();
    mx = fmaxf(fmaxf(red[0], red[1]), fmaxf(red[2], red[3]));
    __syncthreads();
    float se = 0.f;
    for (int i = t; i < N_; i += 256) se += expf(sc[i] - mx);
    se = wredS(se);
    if ((t & 63) == 0) red[t >> 6] = se;
    __syncthreads();
    float s1 = red[0] + red[1] + red[2] + red[3];
    __syncthreads();
    float inv = 1.f / s1;
    float m2 = -1e30f;
    for (int i = t; i < N_; i += 256){
        float p = expf(sc[i] - mx) * inv;
        sc[i] = p;
        if (cp[i] != 0) m2 = fmaxf(m2, p);
    }
    m2 = wredM(m2);
    if ((t & 63) == 0) red[t >> 6] = m2;
    __syncthreads();
    m2 = fmaxf(fmaxf(red[0], red[1]), fmaxf(red[2], red[3]));
    __syncthreads();
    float s2 = 0.f;
    for (int i = t; i < N_; i += 256) if (cp[i] != 0) s2 += expf(sc[i] - m2);
    s2 = wredS(s2);
    if ((t & 63) == 0) red[t >> 6] = s2;
    __syncthreads();
    float lse = m2 + logf(red[0] + red[1] + red[2] + red[3]);
    __syncthreads();
    int a = action[b];
    float ent = 0.f;
    for (int i = t; i < N_; i += 256){
        float lp = (cp[i] != 0 ? sc[i] : NEG_) - lse;
        float pe = expf(lp);
        ent -= pe * lp;
        if (i == a) lps = lp;
    }
    ent = wredS(ent);
    if ((t & 63) == 0) red[t >> 6] = ent;
    __syncthreads();
    if (t == 0){
        out[b]      = (float)a;
        out[16 + b] = lps;
        out[32 + b] = red[0] + red[1] + red[2] + red[3];
    }
}

// ---------------------------------------------------------------------------
extern "C" void kernel_launch(void* const* d_in, const int* in_sizes, int n_in,
                              void* d_out, int out_size, void* d_ws, size_t ws_size,
                              hipStream_t stream) {
    const float* feat = (const float*)d_in[0];
    const int*   adj  = (const int*)d_in[1];
    const int*   cand = (const int*)d_in[2];
    const int*   act  = (const int*)d_in[3];
    const float* W1   = (const float*)d_in[4];
    const float* b1   = (const float*)d_in[5];
    const float* W2   = (const float*)d_in[6];
    const float* b2   = (const float*)d_in[7];
    const float* W3   = (const float*)d_in[8];
    const float* b3   = (const float*)d_in[9];
    const float* ms   = (const float*)d_in[10];
    const float* A1   = (const float*)d_in[11];
    const float* ab1  = (const float*)d_in[12];
    const float* A2   = (const float*)d_in[13];
    const float* ab2  = (const float*)d_in[14];
    const float* A3   = (const float*)d_in[15];
    const float* ab3  = (const float*)d_in[16];
    const float* C1   = (const float*)d_in[17];
    const float* cb1  = (const float*)d_in[18];
    const float* C2   = (const float*)d_in[19];
    const float* cb2  = (const float*)d_in[20];
    float* out = (float*)d_out;

    char* w8 = (char*)d_ws;
    size_t off = 0;
    auto alloc = [&](size_t bytes){ void* p = w8 + off; off += (bytes + 255) & ~(size_t)255; return p; };
    i8*    ATi8  = (i8*)   alloc((size_t)B_ * N_ * N_);
    u16*   Yb16  = (u16*)  alloc((size_t)B_ * H_ * N_ * 2);
    i8*    Yi8A  = (i8*)   alloc((size_t)B_ * H_ * N_);
    i8*    Yi8B  = (i8*)   alloc((size_t)B_ * H_ * N_);
    u16*   hbuf  = (u16*)  alloc((size_t)B_ * N_ * H_ * 2);
    float* degF  = (float*)alloc((size_t)B_ * N_ * 4);      // 131072 B
    float* poolF = (float*)alloc((size_t)B_ * H_ * 4);      // 8192 B
    int*   absm  = (int*)  alloc(48 * 4);                   // 3 stages x 16 batches
    float* dis   = (float*)alloc((size_t)B_ * N_ * 4);
    float* cvec  = (float*)alloc((size_t)B_ * H_ * 4);
    float* scr   = (float*)alloc((size_t)B_ * N_ * 4);
    u16*   WT2   = (u16*)  alloc((size_t)H_ * H_ * 2);
    u16*   WT3   = (u16*)  alloc((size_t)H_ * H_ * 2);
    u16*   A1aT  = (u16*)  alloc((size_t)H_ * H_ * 2);
    u16*   A2T   = (u16*)  alloc((size_t)H_ * H_ * 2);

    // zero deg + pool + absmax accumulators (contiguous region)
    hipMemsetAsync(degF, 0, (size_t)B_ * N_ * 4 + (size_t)B_ * H_ * 4 + 256, stream);

    k_prep<<<dim3(32, 32, 16), 256, 0, stream>>>(adj, ATi8, degF);
    k_misc<<<dim3(384), 256, 0, stream>>>(degF, dis, W2, WT2, W3, WT3, A1, A1aT, A2, A2T);
    k_y1  <<<dim3(8, 16, 16), 256, 0, stream>>>(feat, W1, dis, Yb16, absm + 0);
    k_quant<<<dim3(2048), 256, 0, stream>>>(Yb16, absm + 0, Yi8A);

    k_layer<0><<<dim3(512), 256, 0, stream>>>(ATi8, Yi8A, dis, b1, absm + 0,  WT2, Yb16, absm + 16, nullptr, nullptr);
    k_quant<<<dim3(2048), 256, 0, stream>>>(Yb16, absm + 16, Yi8B);
    k_layer<0><<<dim3(512), 256, 0, stream>>>(ATi8, Yi8B, dis, b2, absm + 16, WT3, Yb16, absm + 32, nullptr, nullptr);
    k_quant<<<dim3(2048), 256, 0, stream>>>(Yb16, absm + 32, Yi8A);
    k_layer<1><<<dim3(512), 256, 0, stream>>>(ATi8, Yi8A, dis, b3, absm + 32, nullptr, nullptr, nullptr, hbuf, poolF);

    k_cv  <<<dim3(16), 256, 0, stream>>>(poolF, ms, A1, ab1, C1, cb1, C2, cb2, cvec, out);
    k_actor<<<dim3(16, 16), 256, 0, stream>>>(hbuf, A1aT, A2T, cvec, ab2, A3, ab3, scr);
    k_sm  <<<dim3(16), 256, 0, stream>>>(scr, cand, act, out);
}